// Round 2
// baseline (257.271 us; speedup 1.0000x reference)
//
#include <hip/hip_runtime.h>
#include <math.h>

#define HD 32      // hidden dim
#define FIN 64     // input features
#define NL 3       // num BernConv layers
#define NC 2       // num classes

#define TILE 8192  // edges per partition tile
#define CAP  3072  // max edges per bucket (mean ~2046, 12 sigma margin)
#define BMAX 1024  // max buckets (N <= 131072 with 128 nodes/bucket)

// fast tanh; |rel err| ~1e-7, threshold 7e-2
__device__ __forceinline__ float fast_tanh(float x) {
    float e = __expf(2.0f * x);
    return 1.0f - 2.0f * __builtin_amdgcn_rcpf(e + 1.0f);
}

// fp32 -> bf16 bits with round-to-nearest-even (values are finite here)
__device__ __forceinline__ unsigned int f2bf(float f) {
    unsigned int u = __float_as_uint(f);
    return (u + 0x7fffu + ((u >> 16) & 1u)) >> 16;
}
__device__ __forceinline__ unsigned int pack2(float lo, float hi) {
    return f2bf(lo) | (f2bf(hi) << 16);
}
// bf16 pair -> fp32 (exact, just bit shifts)
__device__ __forceinline__ float bflo(unsigned int u) { return __uint_as_float(u << 16); }
__device__ __forceinline__ float bfhi(unsigned int u) { return __uint_as_float(u & 0xffff0000u); }

// ---------------- gcursor init ----------------
__global__ __launch_bounds__(256) void init_kernel(int* __restrict__ gcursor, int B) {
    int b = blockIdx.x * 256 + threadIdx.x;
    if (b < B) gcursor[b] = b * CAP;
}

// ---------------- LDS-staged partition: bucket edges by dst>>7 ----------------
__global__ __launch_bounds__(256) void partition_kernel(const int* __restrict__ src,
                                                        const int* __restrict__ dst,
                                                        int* __restrict__ gcursor,
                                                        unsigned int* __restrict__ bucket_buf,
                                                        int E) {
    __shared__ unsigned int vals[TILE];
    __shared__ unsigned short bid[TILE];
    __shared__ int hist[BMAX];
    __shared__ int lcur[BMAX];
    __shared__ int goff[BMAX];
    __shared__ int sc[256];
    int t = threadIdx.x;
    int tile_base = blockIdx.x * TILE;
    int n_tile = min(TILE, E - tile_base);

    for (int i = t; i < BMAX; i += 256) hist[i] = 0;
    __syncthreads();

    unsigned int pk[TILE / 256];
    int bk[TILE / 256];
#pragma unroll
    for (int k = 0; k < TILE / 256; ++k) {
        int e = tile_base + k * 256 + t;
        if (e < E) {
            int s = src[e], d = dst[e];
            int b = d >> 7;
            pk[k] = ((unsigned)s << 7) | (unsigned)(d & 127);
            bk[k] = b;
            atomicAdd(&hist[b], 1);
        } else bk[k] = -1;
    }
    __syncthreads();

    int base4 = t * 4;
    int sum4 = hist[base4] + hist[base4 + 1] + hist[base4 + 2] + hist[base4 + 3];
    sc[t] = sum4;
    __syncthreads();
    for (int off = 1; off < 256; off <<= 1) {
        int v = (t >= off) ? sc[t - off] : 0;
        __syncthreads();
        sc[t] += v;
        __syncthreads();
    }
    int run = sc[t] - sum4;
#pragma unroll
    for (int j = 0; j < 4; ++j) {
        int tmp = hist[base4 + j];
        hist[base4 + j] = run;
        lcur[base4 + j] = run;
        run += tmp;
    }
    __syncthreads();

#pragma unroll
    for (int k = 0; k < TILE / 256; ++k) {
        if (bk[k] >= 0) {
            int pos = atomicAdd(&lcur[bk[k]], 1);
            vals[pos] = pk[k];
            bid[pos] = (unsigned short)bk[k];
        }
    }
    __syncthreads();

    for (int b = t; b < BMAX; b += 256) {
        int cnt = lcur[b] - hist[b];
        goff[b] = (cnt > 0) ? atomicAdd(&gcursor[b], cnt) : 0;
    }
    __syncthreads();

    for (int i = t; i < n_tile; i += 256) {
        int b = bid[i];
        int addr = goff[b] + (i - hist[b]);
        if (addr < (b + 1) * CAP)
            bucket_buf[addr] = vals[i];
    }
}

// ---------------- per-bucket CSR build (in place) ----------------
__global__ __launch_bounds__(256) void bucket_csr_kernel(unsigned int* bucket_buf,
                                                         const int* __restrict__ gcursor,
                                                         int* __restrict__ row_start,
                                                         int* __restrict__ degA,
                                                         float* __restrict__ dinv,
                                                         int N) {
    __shared__ int ldeg[128], lexc[128], lcur2[128];
    __shared__ int colLDS[CAP];
    int b = blockIdx.x;
    int t = threadIdx.x;
    int base = b * CAP;
    int cnt = min(gcursor[b] - base, CAP);

    if (t < 128) ldeg[t] = 0;
    __syncthreads();
    for (int i = t; i < cnt; i += 256)
        atomicAdd(&ldeg[bucket_buf[base + i] & 127], 1);
    __syncthreads();

    if (t < 128) lexc[t] = ldeg[t];
    __syncthreads();
    for (int off = 1; off < 128; off <<= 1) {
        int v = (t >= off && t < 128) ? lexc[t - off] : 0;
        __syncthreads();
        if (t < 128) lexc[t] += v;
        __syncthreads();
    }
    if (t < 128) {
        int ex = lexc[t] - ldeg[t];
        lcur2[t] = ex;
        int node = (b << 7) + t;
        if (node < N) {
            row_start[node] = base + ex;
            degA[node] = ldeg[t];
            dinv[node] = rsqrtf(fmaxf((float)ldeg[t], 1.0f));
        }
    }
    __syncthreads();

    for (int i = t; i < cnt; i += 256) {
        unsigned int v = bucket_buf[base + i];
        int pos = atomicAdd(&lcur2[(int)(v & 127)], 1);
        colLDS[pos] = (int)(v >> 7);
    }
    __syncthreads();
    for (int i = t; i < cnt; i += 256)
        bucket_buf[base + i] = (unsigned int)colLDS[i];   // now = col[]
}

// ---------------- MLP in: h = relu(feat@W1+b1)@W2+b2 ----------------
// 4 lanes per node; lane q owns hidden columns [8q, 8q+8).
// Layer-2 exchange of relu(h1) via LDS broadcast (NOT shfl: runtime-lane
// __shfl lowers to 32 serialized ds_bpermute waits — measured 50 µs, VALUBusy 13%).
// Also emits hs_b = bf16(dinv[n] * h[n]) — the gather operand.
__global__ __launch_bounds__(256) void mlp_kernel(const float* __restrict__ feat,
                                                  const float* __restrict__ W1,
                                                  const float* __restrict__ b1,
                                                  const float* __restrict__ W2,
                                                  const float* __restrict__ b2,
                                                  const float* __restrict__ dinv,
                                                  float* __restrict__ hout,
                                                  uint4* __restrict__ hs_b, int N) {
    __shared__ float4 xA[256];   // relu(h1)[jb..jb+4) per thread — lane-contiguous, conflict-free
    __shared__ float4 xB[256];   // relu(h1)[jb+4..jb+8)
    int lt = threadIdx.x;
    int t = blockIdx.x * 256 + lt;
    int n = t >> 2;
    int q = t & 3;
    int jb = 8 * q;
    int nc = (n < N) ? n : (N - 1);   // clamp for loads; tail threads skip stores only

    // ---- layer 1: h1[j] for my 8 columns (full k) ----
    float h1[8];
#pragma unroll
    for (int j = 0; j < 8; ++j) h1[j] = b1[jb + j];
    const float4* fp = (const float4*)(feat + (size_t)nc * FIN);
#pragma unroll
    for (int k4 = 0; k4 < FIN / 4; ++k4) {
        float4 v = fp[k4];
        const float* w0 = &W1[(k4 * 4 + 0) * HD + jb];
        const float* w1 = &W1[(k4 * 4 + 1) * HD + jb];
        const float* w2 = &W1[(k4 * 4 + 2) * HD + jb];
        const float* w3 = &W1[(k4 * 4 + 3) * HD + jb];
#pragma unroll
        for (int j = 0; j < 8; ++j)
            h1[j] = fmaf(v.w, w3[j],
                    fmaf(v.z, w2[j],
                    fmaf(v.y, w1[j],
                    fmaf(v.x, w0[j], h1[j]))));
    }

    // ---- relu -> LDS exchange (4-lane-group broadcast) ----
    float4 ra = {fmaxf(h1[0], 0.f), fmaxf(h1[1], 0.f), fmaxf(h1[2], 0.f), fmaxf(h1[3], 0.f)};
    float4 rb = {fmaxf(h1[4], 0.f), fmaxf(h1[5], 0.f), fmaxf(h1[6], 0.f), fmaxf(h1[7], 0.f)};
    xA[lt] = ra;
    xB[lt] = rb;
    __syncthreads();

    // ---- layer 2: all 32 relu(h1) from my group's 4 rows, pure-register FMAs ----
    float h2[8];
#pragma unroll
    for (int j = 0; j < 8; ++j) h2[j] = b2[jb + j];
    int g4 = lt & ~3;
#pragma unroll
    for (int qq = 0; qq < 4; ++qq) {
        float4 a = xA[g4 + qq];
        float4 b = xB[g4 + qq];
        float av[8] = {a.x, a.y, a.z, a.w, b.x, b.y, b.z, b.w};
#pragma unroll
        for (int kk = 0; kk < 8; ++kk) {
            int k = qq * 8 + kk;
            const float* w = &W2[k * HD + jb];
#pragma unroll
            for (int j = 0; j < 8; ++j) h2[j] = fmaf(av[kk], w[j], h2[j]);
        }
    }

    if (n >= N) return;

    // ---- write h (fp32) and hs_b (bf16 * dinv) ----
    float4* op = (float4*)(hout + (size_t)n * HD + jb);
    float4 va = {h2[0], h2[1], h2[2], h2[3]};
    float4 vb = {h2[4], h2[5], h2[6], h2[7]};
    op[0] = va;
    op[1] = vb;
    float di = dinv[n];
    uint4 u;
    u.x = pack2(di * h2[0], di * h2[1]);
    u.y = pack2(di * h2[2], di * h2[3]);
    u.z = pack2(di * h2[4], di * h2[5]);
    u.w = pack2(di * h2[6], di * h2[7]);
    hs_b[(size_t)n * 4 + q] = u;
}

// ---------------- gather #1: acc = sum hs[col]; s0 = acc (fp32);
//                  f1s_b = bf16(dinv[n]*(h[n] + dinv[n]*acc)) ----------------
// 4 lanes/node, lane q handles features [8q, 8q+8)
__global__ __launch_bounds__(256) void gather1_kernel(const float* __restrict__ h,
                                                      const uint4* __restrict__ hs_b,
                                                      const float* __restrict__ dinv,
                                                      const int* __restrict__ row_start,
                                                      const int* __restrict__ deg,
                                                      const int* __restrict__ col,
                                                      float* __restrict__ s0,
                                                      uint4* __restrict__ f1s_b, int N) {
    int t = blockIdx.x * 256 + threadIdx.x;
    int n = t >> 2;
    if (n >= N) return;
    int q = t & 3;
    int s = row_start[n];
    int e_end = s + deg[n];
    float acc[8] = {0.f, 0.f, 0.f, 0.f, 0.f, 0.f, 0.f, 0.f};
    for (int e = s; e < e_end; ++e) {
        int c = col[e];
        uint4 v = hs_b[(size_t)c * 4 + q];
        acc[0] += bflo(v.x); acc[1] += bfhi(v.x);
        acc[2] += bflo(v.y); acc[3] += bfhi(v.y);
        acc[4] += bflo(v.z); acc[5] += bfhi(v.z);
        acc[6] += bflo(v.w); acc[7] += bfhi(v.w);
    }
    float di = dinv[n];
    const float4* h4 = (const float4*)h;
    float4 ha = h4[(size_t)n * 8 + 2 * q];
    float4 hb = h4[(size_t)n * 8 + 2 * q + 1];
    float f[8] = {fmaf(di, acc[0], ha.x), fmaf(di, acc[1], ha.y),
                  fmaf(di, acc[2], ha.z), fmaf(di, acc[3], ha.w),
                  fmaf(di, acc[4], hb.x), fmaf(di, acc[5], hb.y),
                  fmaf(di, acc[6], hb.z), fmaf(di, acc[7], hb.w)};
    float4 sa = {acc[0], acc[1], acc[2], acc[3]};
    float4 sb = {acc[4], acc[5], acc[6], acc[7]};
    ((float4*)s0)[(size_t)n * 8 + 2 * q] = sa;
    ((float4*)s0)[(size_t)n * 8 + 2 * q + 1] = sb;
    uint4 u;
    u.x = pack2(di * f[0], di * f[1]);
    u.y = pack2(di * f[2], di * f[3]);
    u.z = pack2(di * f[4], di * f[5]);
    u.w = pack2(di * f[6], di * f[7]);
    f1s_b[(size_t)n * 4 + q] = u;
}

// ---------------- gather #2: t1 = sum f1s[col] (fp32 out) ----------------
__global__ __launch_bounds__(256) void gather2_kernel(const uint4* __restrict__ f1s_b,
                                                      const int* __restrict__ row_start,
                                                      const int* __restrict__ deg,
                                                      const int* __restrict__ col,
                                                      float* __restrict__ t1, int N) {
    int t = blockIdx.x * 256 + threadIdx.x;
    int n = t >> 2;
    if (n >= N) return;
    int q = t & 3;
    int s = row_start[n];
    int e_end = s + deg[n];
    float acc[8] = {0.f, 0.f, 0.f, 0.f, 0.f, 0.f, 0.f, 0.f};
    for (int e = s; e < e_end; ++e) {
        int c = col[e];
        uint4 v = f1s_b[(size_t)c * 4 + q];
        acc[0] += bflo(v.x); acc[1] += bfhi(v.x);
        acc[2] += bflo(v.y); acc[3] += bfhi(v.y);
        acc[4] += bflo(v.z); acc[5] += bfhi(v.z);
        acc[6] += bflo(v.w); acc[7] += bfhi(v.w);
    }
    float4 sa = {acc[0], acc[1], acc[2], acc[3]};
    float4 sb = {acc[4], acc[5], acc[6], acc[7]};
    ((float4*)t1)[(size_t)n * 8 + 2 * q] = sa;
    ((float4*)t1)[(size_t)n * 8 + 2 * q + 1] = sb;
}

// ---------------- fused epilogue ----------------
// 4 lanes per node; lane q owns hidden columns [8q, 8q+8).
// Bases: f2 = h + d*s0 + d*t1; g1 = h + d*s0 - d*t1; g2 = h - 3d*s0 + d*t1
// Per-k scalars (f2/g1/g2, vf/vg/vh) are recomputed in all 4 lanes (L1-broadcast
// loads); logit dot-products reduced across the group with __shfl_xor.
__global__ __launch_bounds__(256) void final_kernel(const float* __restrict__ h,
                                                    const float* __restrict__ s0,
                                                    const float* __restrict__ t1,
                                                    const float* __restrict__ dinv,
                                                    const float* __restrict__ W2,
                                                    const float* __restrict__ b2,
                                                    const float* __restrict__ Wc,
                                                    const float* __restrict__ bc,
                                                    const float* __restrict__ wbern,
                                                    float* __restrict__ out, int N) {
    int t = blockIdx.x * 256 + threadIdx.x;
    int n = t >> 2;
    if (n >= N) return;
    int q = t & 3;
    int jb = 8 * q;
    float di = dinv[n];

    float4 b2a = ((const float4*)b2)[2 * q];
    float4 b2b = ((const float4*)b2)[2 * q + 1];
    float b2v[8] = {b2a.x, b2a.y, b2a.z, b2a.w, b2b.x, b2b.y, b2b.z, b2b.w};

    float xp[8];
#pragma unroll
    for (int j = 0; j < 8; ++j) xp[j] = b2v[j];
    float uf[8], ug[8], uh[8];
#pragma unroll
    for (int j = 0; j < 8; ++j) { uf[j] = 0.f; ug[j] = 0.f; uh[j] = 0.f; }
    float vf0 = 0.f, vf1 = 0.f, vg0 = 0.f, vg1 = 0.f, vh0 = 0.f, vh1 = 0.f;

    const float4* h4  = (const float4*)(h  + (size_t)n * HD);
    const float4* s04 = (const float4*)(s0 + (size_t)n * HD);
    const float4* t14 = (const float4*)(t1 + (size_t)n * HD);
    const float2* wc2 = (const float2*)Wc;

#pragma unroll
    for (int q8 = 0; q8 < 8; ++q8) {
        float4 hv = h4[q8];
        float4 av = s04[q8];
        float4 bv = t14[q8];
        float hq[4] = {hv.x, hv.y, hv.z, hv.w};
        float da[4] = {di * av.x, di * av.y, di * av.z, di * av.w};
        float db[4] = {di * bv.x, di * bv.y, di * bv.z, di * bv.w};
#pragma unroll
        for (int r = 0; r < 4; ++r) {
            int k = q8 * 4 + r;
            float f2 = hq[r] + da[r] + db[r];
            float g1 = hq[r] + da[r] - db[r];
            float g2 = hq[r] - 3.0f * da[r] + db[r];
            const float4* w4 = (const float4*)&W2[k * HD + jb];
            float4 wA = w4[0], wB = w4[1];
            float wv[8] = {wA.x, wA.y, wA.z, wA.w, wB.x, wB.y, wB.z, wB.w};
#pragma unroll
            for (int j = 0; j < 8; ++j) {
                xp[j] = fmaf(hq[r], wv[j], xp[j]);
                uf[j] = fmaf(f2, wv[j], uf[j]);
                ug[j] = fmaf(g1, wv[j], ug[j]);
                uh[j] = fmaf(g2, wv[j], uh[j]);
            }
            float2 wc = wc2[k];
            vf0 = fmaf(f2, wc.x, vf0); vf1 = fmaf(f2, wc.y, vf1);
            vg0 = fmaf(g1, wc.x, vg0); vg1 = fmaf(g1, wc.y, vg1);
            vh0 = fmaf(g2, wc.x, vh0); vh1 = fmaf(g2, wc.y, vh1);
        }
    }

#pragma unroll
    for (int j = 0; j < 8; ++j) xp[j] = fast_tanh(xp[j]);

    float logits[NL];
#pragma unroll
    for (int i = 0; i < NL; ++i) {
        float wa = 0.25f * fmaxf(wbern[i * 3 + 0], 0.0f);
        float wb = 0.50f * fmaxf(wbern[i * 3 + 1], 0.0f);
        float wc = 0.25f * fmaxf(wbern[i * 3 + 2], 0.0f);
        float lg = 0.0f;
#pragma unroll
        for (int j = 0; j < 8; ++j) {
            float p = fmaf(wa, uf[j], fmaf(wb, ug[j], fmaf(wc, uh[j], b2v[j])));
            lg = fmaf(fast_tanh(p), xp[j], lg);
        }
        lg += __shfl_xor(lg, 1);
        lg += __shfl_xor(lg, 2);
        logits[i] = lg;
    }

    float m = fmaxf(logits[0], fmaxf(logits[1], logits[2]));
    float e0 = __expf(logits[0] - m), e1 = __expf(logits[1] - m), e2 = __expf(logits[2] - m);
    float inv = 1.0f / (e0 + e1 + e2);
    float scs[NL] = {e0 * inv, e1 * inv, e2 * inv};

    float A = 0.0f, B = 0.0f, Cc = 0.0f;
#pragma unroll
    for (int i = 0; i < NL; ++i) {
        A  += scs[i] * 0.25f * fmaxf(wbern[i * 3 + 0], 0.0f);
        B  += scs[i] * 0.50f * fmaxf(wbern[i * 3 + 1], 0.0f);
        Cc += scs[i] * 0.25f * fmaxf(wbern[i * 3 + 2], 0.0f);
    }
    if (q == 0) {
        float2 o;
        o.x = bc[0] + A * vf0 + B * vg0 + Cc * vh0;
        o.y = bc[1] + A * vf1 + B * vg1 + Cc * vh1;
        ((float2*)out)[n] = o;
    }
}

extern "C" void kernel_launch(void* const* d_in, const int* in_sizes, int n_in,
                              void* d_out, int out_size, void* d_ws, size_t ws_size,
                              hipStream_t stream) {
    const float* feature = (const float*)d_in[0];
    const float* W1 = (const float*)d_in[1];
    const float* b1 = (const float*)d_in[2];
    const float* W2 = (const float*)d_in[3];
    const float* b2 = (const float*)d_in[4];
    const float* Wc = (const float*)d_in[5];
    const float* bc = (const float*)d_in[6];
    const float* wbern = (const float*)d_in[7];
    const int* src = (const int*)d_in[8];
    const int* dst = (const int*)d_in[9];

    const int N = in_sizes[0] / FIN;   // 100000
    const int E = in_sizes[8];         // 1600000
    const int B = (N + 127) >> 7;      // 782 buckets

    // workspace layout
    char* p = (char*)d_ws;
    size_t Np = ((size_t)N + 255) & ~(size_t)255;
    size_t N32 = (size_t)N * HD;
    int* gcursor   = (int*)p;              p += ((size_t)BMAX) * 4;
    int* row_start = (int*)p;              p += Np * 4;
    int* degA      = (int*)p;              p += Np * 4;
    float* dinv    = (float*)p;            p += Np * 4;
    unsigned int* bucket_buf = (unsigned int*)p;  p += (size_t)B * CAP * 4;  // becomes col[]
    float* h    = (float*)p;               p += N32 * 4;
    float* s0   = (float*)p;               p += N32 * 4;
    float* t1   = (float*)p;               p += N32 * 4;
    uint4* hs_b = (uint4*)p;               p += N32 * 2;   // bf16, 64B/row
    uint4* f1s_b= (uint4*)p;               p += N32 * 2;

    int bG = ((N * 4) + 255) / 256;        // 4 lanes per node
    int nTiles = (E + TILE - 1) / TILE;

    init_kernel<<<(B + 255) / 256, 256, 0, stream>>>(gcursor, B);
    partition_kernel<<<nTiles, 256, 0, stream>>>(src, dst, gcursor, bucket_buf, E);
    bucket_csr_kernel<<<B, 256, 0, stream>>>(bucket_buf, gcursor, row_start, degA, dinv, N);

    mlp_kernel<<<bG, 256, 0, stream>>>(feature, W1, b1, W2, b2, dinv, h, hs_b, N);

    const int* col = (const int*)bucket_buf;
    gather1_kernel<<<bG, 256, 0, stream>>>(h, hs_b, dinv, row_start, degA, col, s0, f1s_b, N);
    gather2_kernel<<<bG, 256, 0, stream>>>(f1s_b, row_start, degA, col, t1, N);

    final_kernel<<<bG, 256, 0, stream>>>(h, s0, t1, dinv, W2, b2, Wc, bc,
                                         wbern, (float*)d_out, N);
}

// Round 3
// 223.769 us; speedup vs baseline: 1.1497x; 1.1497x over previous
//
#include <hip/hip_runtime.h>
#include <math.h>

#define HD 32      // hidden dim
#define FIN 64     // input features
#define NL 3       // num BernConv layers
#define NC 2       // num classes

#define TILE 8192  // edges per partition tile
#define CAP  3072  // max edges per bucket (mean ~2046, 12 sigma margin)
#define BMAX 1024  // max buckets (N <= 131072 with 128 nodes/bucket)

typedef __attribute__((ext_vector_type(8))) short bf16x8;
typedef __attribute__((ext_vector_type(4))) float f32x4;

// fast tanh; |rel err| ~1e-7, threshold 7e-2
__device__ __forceinline__ float fast_tanh(float x) {
    float e = __expf(2.0f * x);
    return 1.0f - 2.0f * __builtin_amdgcn_rcpf(e + 1.0f);
}

// fp32 -> bf16 bits with round-to-nearest-even (values are finite here)
__device__ __forceinline__ unsigned int f2bf(float f) {
    unsigned int u = __float_as_uint(f);
    return (u + 0x7fffu + ((u >> 16) & 1u)) >> 16;
}
__device__ __forceinline__ unsigned int pack2(float lo, float hi) {
    return f2bf(lo) | (f2bf(hi) << 16);
}
// bf16 pair -> fp32 (exact, just bit shifts)
__device__ __forceinline__ float bflo(unsigned int u) { return __uint_as_float(u << 16); }
__device__ __forceinline__ float bfhi(unsigned int u) { return __uint_as_float(u & 0xffff0000u); }

// ---------------- gcursor init ----------------
__global__ __launch_bounds__(256) void init_kernel(int* __restrict__ gcursor, int B) {
    int b = blockIdx.x * 256 + threadIdx.x;
    if (b < B) gcursor[b] = b * CAP;
}

// ---------------- LDS-staged partition: bucket edges by dst>>7 ----------------
__global__ __launch_bounds__(256) void partition_kernel(const int* __restrict__ src,
                                                        const int* __restrict__ dst,
                                                        int* __restrict__ gcursor,
                                                        unsigned int* __restrict__ bucket_buf,
                                                        int E) {
    __shared__ unsigned int vals[TILE];
    __shared__ unsigned short bid[TILE];
    __shared__ int hist[BMAX];
    __shared__ int lcur[BMAX];
    __shared__ int goff[BMAX];
    __shared__ int sc[256];
    int t = threadIdx.x;
    int tile_base = blockIdx.x * TILE;
    int n_tile = min(TILE, E - tile_base);

    for (int i = t; i < BMAX; i += 256) hist[i] = 0;
    __syncthreads();

    unsigned int pk[TILE / 256];
    int bk[TILE / 256];
#pragma unroll
    for (int k = 0; k < TILE / 256; ++k) {
        int e = tile_base + k * 256 + t;
        if (e < E) {
            int s = src[e], d = dst[e];
            int b = d >> 7;
            pk[k] = ((unsigned)s << 7) | (unsigned)(d & 127);
            bk[k] = b;
            atomicAdd(&hist[b], 1);
        } else bk[k] = -1;
    }
    __syncthreads();

    int base4 = t * 4;
    int sum4 = hist[base4] + hist[base4 + 1] + hist[base4 + 2] + hist[base4 + 3];
    sc[t] = sum4;
    __syncthreads();
    for (int off = 1; off < 256; off <<= 1) {
        int v = (t >= off) ? sc[t - off] : 0;
        __syncthreads();
        sc[t] += v;
        __syncthreads();
    }
    int run = sc[t] - sum4;
#pragma unroll
    for (int j = 0; j < 4; ++j) {
        int tmp = hist[base4 + j];
        hist[base4 + j] = run;
        lcur[base4 + j] = run;
        run += tmp;
    }
    __syncthreads();

#pragma unroll
    for (int k = 0; k < TILE / 256; ++k) {
        if (bk[k] >= 0) {
            int pos = atomicAdd(&lcur[bk[k]], 1);
            vals[pos] = pk[k];
            bid[pos] = (unsigned short)bk[k];
        }
    }
    __syncthreads();

    for (int b = t; b < BMAX; b += 256) {
        int cnt = lcur[b] - hist[b];
        goff[b] = (cnt > 0) ? atomicAdd(&gcursor[b], cnt) : 0;
    }
    __syncthreads();

    for (int i = t; i < n_tile; i += 256) {
        int b = bid[i];
        int addr = goff[b] + (i - hist[b]);
        if (addr < (b + 1) * CAP)
            bucket_buf[addr] = vals[i];
    }
}

// ---------------- per-bucket CSR build (in place) ----------------
__global__ __launch_bounds__(256) void bucket_csr_kernel(unsigned int* bucket_buf,
                                                         const int* __restrict__ gcursor,
                                                         int* __restrict__ row_start,
                                                         int* __restrict__ degA,
                                                         float* __restrict__ dinv,
                                                         int N) {
    __shared__ int ldeg[128], lexc[128], lcur2[128];
    __shared__ int colLDS[CAP];
    int b = blockIdx.x;
    int t = threadIdx.x;
    int base = b * CAP;
    int cnt = min(gcursor[b] - base, CAP);

    if (t < 128) ldeg[t] = 0;
    __syncthreads();
    for (int i = t; i < cnt; i += 256)
        atomicAdd(&ldeg[bucket_buf[base + i] & 127], 1);
    __syncthreads();

    if (t < 128) lexc[t] = ldeg[t];
    __syncthreads();
    for (int off = 1; off < 128; off <<= 1) {
        int v = (t >= off && t < 128) ? lexc[t - off] : 0;
        __syncthreads();
        if (t < 128) lexc[t] += v;
        __syncthreads();
    }
    if (t < 128) {
        int ex = lexc[t] - ldeg[t];
        lcur2[t] = ex;
        int node = (b << 7) + t;
        if (node < N) {
            row_start[node] = base + ex;
            degA[node] = ldeg[t];
            dinv[node] = rsqrtf(fmaxf((float)ldeg[t], 1.0f));
        }
    }
    __syncthreads();

    for (int i = t; i < cnt; i += 256) {
        unsigned int v = bucket_buf[base + i];
        int pos = atomicAdd(&lcur2[(int)(v & 127)], 1);
        colLDS[pos] = (int)(v >> 7);
    }
    __syncthreads();
    for (int i = t; i < cnt; i += 256)
        bucket_buf[base + i] = (unsigned int)colLDS[i];   // now = col[]
}

// ---------------- MLP in via MFMA: h = relu(feat@W1+b1)@W2+b2 ----------------
// Previous per-lane VMEM weight loads = 1.2 GB L1 traffic (~50 us, VALUBusy 13%).
// Now: weights staged once per block in LDS as bf16 fragments; 4 waves x 16-node
// M-tiles; mfma_f32_16x16x32_bf16 for both layers. A/B frags use a COMMON
// k-bijection (k = 8*(lane>>4)+e) so the true per-slot k order cancels;
// C/D layout (col=lane&15, row=4*(lane>>4)+reg) is HW-verified.
__global__ __launch_bounds__(256) void mlp_kernel(const float* __restrict__ feat,
                                                  const float* __restrict__ W1,
                                                  const float* __restrict__ b1,
                                                  const float* __restrict__ W2,
                                                  const float* __restrict__ b2,
                                                  const float* __restrict__ dinv,
                                                  float* __restrict__ hout,
                                                  uint4* __restrict__ hs_b, int N) {
    __shared__ unsigned short w1t[32][72];      // W1^T [j][k], pad 64->72 (row 144B, 16B-aligned)
    __shared__ unsigned short w2t[32][40];      // W2^T [j][k], pad 32->40 (row 80B)
    __shared__ unsigned short h1t[4][16][40];   // per-wave relu(h1) [row][j] bf16
    __shared__ unsigned short h2t[4][16][40];   // per-wave dinv*h2   [row][j] bf16

    int lt = threadIdx.x;
    // cooperative weight staging (fp32 -> bf16, transposed)
    for (int i = lt; i < FIN * HD; i += 256) {
        int k = i >> 5, j = i & 31;
        w1t[j][k] = (unsigned short)f2bf(W1[i]);
    }
    for (int i = lt; i < HD * HD; i += 256) {
        int k = i >> 5, j = i & 31;
        w2t[j][k] = (unsigned short)f2bf(W2[i]);
    }
    __syncthreads();

    int w = lt >> 6;            // wave id 0..3
    int l = lt & 63;            // lane
    int g = l >> 4;             // lane group 0..3
    int c = l & 15;             // tile row (A) / tile col (B,D)
    int base = blockIdx.x * 64 + w * 16;   // first node of this wave's 16-row tile

    // ---- layer-1 A fragments: feat rows (bf16 on the fly), k = ks*32 + 8g + e ----
    int row = base + c;
    int rowc = (row < N) ? row : (N - 1);
    const float* fr = feat + (size_t)rowc * FIN;
    bf16x8 a1[2];
#pragma unroll
    for (int ks = 0; ks < 2; ++ks) {
        const float4* p = (const float4*)(fr + ks * 32 + 8 * g);
        float4 u0 = p[0], u1 = p[1];
        bf16x8 a;
        a[0] = (short)f2bf(u0.x); a[1] = (short)f2bf(u0.y);
        a[2] = (short)f2bf(u0.z); a[3] = (short)f2bf(u0.w);
        a[4] = (short)f2bf(u1.x); a[5] = (short)f2bf(u1.y);
        a[6] = (short)f2bf(u1.z); a[7] = (short)f2bf(u1.w);
        a1[ks] = a;
    }

    // ---- layer 1 MFMA: acc[nt] = sum_ks feat_tile @ W1[:, nt*16..] ----
    f32x4 acc[2];
#pragma unroll
    for (int nt = 0; nt < 2; ++nt) { acc[nt][0] = 0.f; acc[nt][1] = 0.f; acc[nt][2] = 0.f; acc[nt][3] = 0.f; }
#pragma unroll
    for (int nt = 0; nt < 2; ++nt) {
#pragma unroll
        for (int ks = 0; ks < 2; ++ks) {
            bf16x8 b = *(const bf16x8*)&w1t[nt * 16 + c][ks * 32 + 8 * g];
            acc[nt] = __builtin_amdgcn_mfma_f32_16x16x32_bf16(a1[ks], b, acc[nt], 0, 0, 0);
        }
    }

    // ---- bias + relu -> bf16 LDS tile (row-major) ----
    float b1v0 = b1[c], b1v1 = b1[16 + c];
#pragma unroll
    for (int r = 0; r < 4; ++r) {
        h1t[w][4 * g + r][c]      = (unsigned short)f2bf(fmaxf(acc[0][r] + b1v0, 0.0f));
        h1t[w][4 * g + r][16 + c] = (unsigned short)f2bf(fmaxf(acc[1][r] + b1v1, 0.0f));
    }
    __syncthreads();

    // ---- layer 2 MFMA: A frag from h1 tile (row c, k = 8g+e) ----
    bf16x8 a2 = *(const bf16x8*)&h1t[w][c][8 * g];
    f32x4 acc2[2];
#pragma unroll
    for (int nt = 0; nt < 2; ++nt) { acc2[nt][0] = 0.f; acc2[nt][1] = 0.f; acc2[nt][2] = 0.f; acc2[nt][3] = 0.f; }
#pragma unroll
    for (int nt = 0; nt < 2; ++nt) {
        bf16x8 b = *(const bf16x8*)&w2t[nt * 16 + c][8 * g];
        acc2[nt] = __builtin_amdgcn_mfma_f32_16x16x32_bf16(a2, b, acc2[nt], 0, 0, 0);
    }

    // ---- bias, write h (fp32) + stage dinv*h2 bf16 for hs_b packing ----
    float b2v0 = b2[c], b2v1 = b2[16 + c];
#pragma unroll
    for (int r = 0; r < 4; ++r) {
        int rr = base + 4 * g + r;
        int rc = (rr < N) ? rr : (N - 1);
        float dv = dinv[rc];
        float v0 = acc2[0][r] + b2v0;
        float v1 = acc2[1][r] + b2v1;
        if (rr < N) {
            hout[(size_t)rr * HD + c]      = v0;
            hout[(size_t)rr * HD + 16 + c] = v1;
        }
        h2t[w][4 * g + r][c]      = (unsigned short)f2bf(dv * v0);
        h2t[w][4 * g + r][16 + c] = (unsigned short)f2bf(dv * v1);
    }
    __syncthreads();

    // ---- pack hs_b: lane handles tile-row c, feature block g (8 bf16 = 16B) ----
    int nrow = base + c;
    if (nrow < N) {
        uint4 u = *(const uint4*)&h2t[w][c][8 * g];
        hs_b[(size_t)nrow * 4 + g] = u;
    }
}

// ---------------- gather #1: acc = sum hs[col]; s0 = acc (fp32);
//                  f1s_b = bf16(dinv[n]*(h[n] + dinv[n]*acc)) ----------------
// 4 lanes/node, lane q handles features [8q, 8q+8)
__global__ __launch_bounds__(256) void gather1_kernel(const float* __restrict__ h,
                                                      const uint4* __restrict__ hs_b,
                                                      const float* __restrict__ dinv,
                                                      const int* __restrict__ row_start,
                                                      const int* __restrict__ deg,
                                                      const int* __restrict__ col,
                                                      float* __restrict__ s0,
                                                      uint4* __restrict__ f1s_b, int N) {
    int t = blockIdx.x * 256 + threadIdx.x;
    int n = t >> 2;
    if (n >= N) return;
    int q = t & 3;
    int s = row_start[n];
    int e_end = s + deg[n];
    float acc[8] = {0.f, 0.f, 0.f, 0.f, 0.f, 0.f, 0.f, 0.f};
    for (int e = s; e < e_end; ++e) {
        int c = col[e];
        uint4 v = hs_b[(size_t)c * 4 + q];
        acc[0] += bflo(v.x); acc[1] += bfhi(v.x);
        acc[2] += bflo(v.y); acc[3] += bfhi(v.y);
        acc[4] += bflo(v.z); acc[5] += bfhi(v.z);
        acc[6] += bflo(v.w); acc[7] += bfhi(v.w);
    }
    float di = dinv[n];
    const float4* h4 = (const float4*)h;
    float4 ha = h4[(size_t)n * 8 + 2 * q];
    float4 hb = h4[(size_t)n * 8 + 2 * q + 1];
    float f[8] = {fmaf(di, acc[0], ha.x), fmaf(di, acc[1], ha.y),
                  fmaf(di, acc[2], ha.z), fmaf(di, acc[3], ha.w),
                  fmaf(di, acc[4], hb.x), fmaf(di, acc[5], hb.y),
                  fmaf(di, acc[6], hb.z), fmaf(di, acc[7], hb.w)};
    float4 sa = {acc[0], acc[1], acc[2], acc[3]};
    float4 sb = {acc[4], acc[5], acc[6], acc[7]};
    ((float4*)s0)[(size_t)n * 8 + 2 * q] = sa;
    ((float4*)s0)[(size_t)n * 8 + 2 * q + 1] = sb;
    uint4 u;
    u.x = pack2(di * f[0], di * f[1]);
    u.y = pack2(di * f[2], di * f[3]);
    u.z = pack2(di * f[4], di * f[5]);
    u.w = pack2(di * f[6], di * f[7]);
    f1s_b[(size_t)n * 4 + q] = u;
}

// ---------------- gather #2: t1 = sum f1s[col] (fp32 out) ----------------
__global__ __launch_bounds__(256) void gather2_kernel(const uint4* __restrict__ f1s_b,
                                                      const int* __restrict__ row_start,
                                                      const int* __restrict__ deg,
                                                      const int* __restrict__ col,
                                                      float* __restrict__ t1, int N) {
    int t = blockIdx.x * 256 + threadIdx.x;
    int n = t >> 2;
    if (n >= N) return;
    int q = t & 3;
    int s = row_start[n];
    int e_end = s + deg[n];
    float acc[8] = {0.f, 0.f, 0.f, 0.f, 0.f, 0.f, 0.f, 0.f};
    for (int e = s; e < e_end; ++e) {
        int c = col[e];
        uint4 v = f1s_b[(size_t)c * 4 + q];
        acc[0] += bflo(v.x); acc[1] += bfhi(v.x);
        acc[2] += bflo(v.y); acc[3] += bfhi(v.y);
        acc[4] += bflo(v.z); acc[5] += bfhi(v.z);
        acc[6] += bflo(v.w); acc[7] += bfhi(v.w);
    }
    float4 sa = {acc[0], acc[1], acc[2], acc[3]};
    float4 sb = {acc[4], acc[5], acc[6], acc[7]};
    ((float4*)t1)[(size_t)n * 8 + 2 * q] = sa;
    ((float4*)t1)[(size_t)n * 8 + 2 * q + 1] = sb;
}

// ---------------- fused epilogue ----------------
// 4 lanes per node; lane q owns hidden columns [8q, 8q+8).
// Bases: f2 = h + d*s0 + d*t1; g1 = h + d*s0 - d*t1; g2 = h - 3d*s0 + d*t1
__global__ __launch_bounds__(256) void final_kernel(const float* __restrict__ h,
                                                    const float* __restrict__ s0,
                                                    const float* __restrict__ t1,
                                                    const float* __restrict__ dinv,
                                                    const float* __restrict__ W2,
                                                    const float* __restrict__ b2,
                                                    const float* __restrict__ Wc,
                                                    const float* __restrict__ bc,
                                                    const float* __restrict__ wbern,
                                                    float* __restrict__ out, int N) {
    int t = blockIdx.x * 256 + threadIdx.x;
    int n = t >> 2;
    if (n >= N) return;
    int q = t & 3;
    int jb = 8 * q;
    float di = dinv[n];

    float4 b2a = ((const float4*)b2)[2 * q];
    float4 b2b = ((const float4*)b2)[2 * q + 1];
    float b2v[8] = {b2a.x, b2a.y, b2a.z, b2a.w, b2b.x, b2b.y, b2b.z, b2b.w};

    float xp[8];
#pragma unroll
    for (int j = 0; j < 8; ++j) xp[j] = b2v[j];
    float uf[8], ug[8], uh[8];
#pragma unroll
    for (int j = 0; j < 8; ++j) { uf[j] = 0.f; ug[j] = 0.f; uh[j] = 0.f; }
    float vf0 = 0.f, vf1 = 0.f, vg0 = 0.f, vg1 = 0.f, vh0 = 0.f, vh1 = 0.f;

    const float4* h4  = (const float4*)(h  + (size_t)n * HD);
    const float4* s04 = (const float4*)(s0 + (size_t)n * HD);
    const float4* t14 = (const float4*)(t1 + (size_t)n * HD);
    const float2* wc2 = (const float2*)Wc;

#pragma unroll
    for (int q8 = 0; q8 < 8; ++q8) {
        float4 hv = h4[q8];
        float4 av = s04[q8];
        float4 bv = t14[q8];
        float hq[4] = {hv.x, hv.y, hv.z, hv.w};
        float da[4] = {di * av.x, di * av.y, di * av.z, di * av.w};
        float db[4] = {di * bv.x, di * bv.y, di * bv.z, di * bv.w};
#pragma unroll
        for (int r = 0; r < 4; ++r) {
            int k = q8 * 4 + r;
            float f2 = hq[r] + da[r] + db[r];
            float g1 = hq[r] + da[r] - db[r];
            float g2 = hq[r] - 3.0f * da[r] + db[r];
            const float4* w4 = (const float4*)&W2[k * HD + jb];
            float4 wA = w4[0], wB = w4[1];
            float wv[8] = {wA.x, wA.y, wA.z, wA.w, wB.x, wB.y, wB.z, wB.w};
#pragma unroll
            for (int j = 0; j < 8; ++j) {
                xp[j] = fmaf(hq[r], wv[j], xp[j]);
                uf[j] = fmaf(f2, wv[j], uf[j]);
                ug[j] = fmaf(g1, wv[j], ug[j]);
                uh[j] = fmaf(g2, wv[j], uh[j]);
            }
            float2 wc = wc2[k];
            vf0 = fmaf(f2, wc.x, vf0); vf1 = fmaf(f2, wc.y, vf1);
            vg0 = fmaf(g1, wc.x, vg0); vg1 = fmaf(g1, wc.y, vg1);
            vh0 = fmaf(g2, wc.x, vh0); vh1 = fmaf(g2, wc.y, vh1);
        }
    }

#pragma unroll
    for (int j = 0; j < 8; ++j) xp[j] = fast_tanh(xp[j]);

    float logits[NL];
#pragma unroll
    for (int i = 0; i < NL; ++i) {
        float wa = 0.25f * fmaxf(wbern[i * 3 + 0], 0.0f);
        float wb = 0.50f * fmaxf(wbern[i * 3 + 1], 0.0f);
        float wc = 0.25f * fmaxf(wbern[i * 3 + 2], 0.0f);
        float lg = 0.0f;
#pragma unroll
        for (int j = 0; j < 8; ++j) {
            float p = fmaf(wa, uf[j], fmaf(wb, ug[j], fmaf(wc, uh[j], b2v[j])));
            lg = fmaf(fast_tanh(p), xp[j], lg);
        }
        lg += __shfl_xor(lg, 1);
        lg += __shfl_xor(lg, 2);
        logits[i] = lg;
    }

    float m = fmaxf(logits[0], fmaxf(logits[1], logits[2]));
    float e0 = __expf(logits[0] - m), e1 = __expf(logits[1] - m), e2 = __expf(logits[2] - m);
    float inv = 1.0f / (e0 + e1 + e2);
    float scs[NL] = {e0 * inv, e1 * inv, e2 * inv};

    float A = 0.0f, B = 0.0f, Cc = 0.0f;
#pragma unroll
    for (int i = 0; i < NL; ++i) {
        A  += scs[i] * 0.25f * fmaxf(wbern[i * 3 + 0], 0.0f);
        B  += scs[i] * 0.50f * fmaxf(wbern[i * 3 + 1], 0.0f);
        Cc += scs[i] * 0.25f * fmaxf(wbern[i * 3 + 2], 0.0f);
    }
    if (q == 0) {
        float2 o;
        o.x = bc[0] + A * vf0 + B * vg0 + Cc * vh0;
        o.y = bc[1] + A * vf1 + B * vg1 + Cc * vh1;
        ((float2*)out)[n] = o;
    }
}

extern "C" void kernel_launch(void* const* d_in, const int* in_sizes, int n_in,
                              void* d_out, int out_size, void* d_ws, size_t ws_size,
                              hipStream_t stream) {
    const float* feature = (const float*)d_in[0];
    const float* W1 = (const float*)d_in[1];
    const float* b1 = (const float*)d_in[2];
    const float* W2 = (const float*)d_in[3];
    const float* b2 = (const float*)d_in[4];
    const float* Wc = (const float*)d_in[5];
    const float* bc = (const float*)d_in[6];
    const float* wbern = (const float*)d_in[7];
    const int* src = (const int*)d_in[8];
    const int* dst = (const int*)d_in[9];

    const int N = in_sizes[0] / FIN;   // 100000
    const int E = in_sizes[8];         // 1600000
    const int B = (N + 127) >> 7;      // 782 buckets

    // workspace layout
    char* p = (char*)d_ws;
    size_t Np = ((size_t)N + 255) & ~(size_t)255;
    size_t N32 = (size_t)N * HD;
    int* gcursor   = (int*)p;              p += ((size_t)BMAX) * 4;
    int* row_start = (int*)p;              p += Np * 4;
    int* degA      = (int*)p;              p += Np * 4;
    float* dinv    = (float*)p;            p += Np * 4;
    unsigned int* bucket_buf = (unsigned int*)p;  p += (size_t)B * CAP * 4;  // becomes col[]
    float* h    = (float*)p;               p += N32 * 4;
    float* s0   = (float*)p;               p += N32 * 4;
    float* t1   = (float*)p;               p += N32 * 4;
    uint4* hs_b = (uint4*)p;               p += N32 * 2;   // bf16, 64B/row
    uint4* f1s_b= (uint4*)p;               p += N32 * 2;

    int bG = ((N * 4) + 255) / 256;        // 4 lanes per node
    int bM = (N + 63) / 64;                // 64 nodes per block (4 waves x 16)
    int nTiles = (E + TILE - 1) / TILE;

    init_kernel<<<(B + 255) / 256, 256, 0, stream>>>(gcursor, B);
    partition_kernel<<<nTiles, 256, 0, stream>>>(src, dst, gcursor, bucket_buf, E);
    bucket_csr_kernel<<<B, 256, 0, stream>>>(bucket_buf, gcursor, row_start, degA, dinv, N);

    mlp_kernel<<<bM, 256, 0, stream>>>(feature, W1, b1, W2, b2, dinv, h, hs_b, N);

    const int* col = (const int*)bucket_buf;
    gather1_kernel<<<bG, 256, 0, stream>>>(h, hs_b, dinv, row_start, degA, col, s0, f1s_b, N);
    gather2_kernel<<<bG, 256, 0, stream>>>(f1s_b, row_start, degA, col, t1, N);

    final_kernel<<<bG, 256, 0, stream>>>(h, s0, t1, dinv, W2, b2, Wc, bc,
                                         wbern, (float*)d_out, N);
}

// Round 4
// 216.718 us; speedup vs baseline: 1.1871x; 1.0325x over previous
//
#include <hip/hip_runtime.h>
#include <math.h>

#define HD 32      // hidden dim
#define FIN 64     // input features
#define NL 3       // num BernConv layers
#define NC 2       // num classes

#define TILE 4096  // edges per partition tile (391 blocks: >1/CU, half the VGPR staging)
#define CAP  3072  // max edges per bucket (mean ~2046, 12 sigma margin)
#define BMAX 1024  // max buckets (N <= 131072 with 128 nodes/bucket)

typedef __attribute__((ext_vector_type(8))) short bf16x8;
typedef __attribute__((ext_vector_type(4))) float f32x4;

// fast tanh; |rel err| ~1e-7, threshold 7e-2
__device__ __forceinline__ float fast_tanh(float x) {
    float e = __expf(2.0f * x);
    return 1.0f - 2.0f * __builtin_amdgcn_rcpf(e + 1.0f);
}

// fp32 -> bf16 bits with round-to-nearest-even (values are finite here)
__device__ __forceinline__ unsigned int f2bf(float f) {
    unsigned int u = __float_as_uint(f);
    return (u + 0x7fffu + ((u >> 16) & 1u)) >> 16;
}
__device__ __forceinline__ unsigned int pack2(float lo, float hi) {
    return f2bf(lo) | (f2bf(hi) << 16);
}
// bf16 pair -> fp32 (exact, just bit shifts)
__device__ __forceinline__ float bflo(unsigned int u) { return __uint_as_float(u << 16); }
__device__ __forceinline__ float bfhi(unsigned int u) { return __uint_as_float(u & 0xffff0000u); }

// ---------------- gcursor init ----------------
__global__ __launch_bounds__(256) void init_kernel(int* __restrict__ gcursor, int B) {
    int b = blockIdx.x * 256 + threadIdx.x;
    if (b < B) gcursor[b] = b * CAP;
}

// ---------------- LDS-staged partition: bucket edges by dst>>7 ----------------
__global__ __launch_bounds__(256) void partition_kernel(const int* __restrict__ src,
                                                        const int* __restrict__ dst,
                                                        int* __restrict__ gcursor,
                                                        unsigned int* __restrict__ bucket_buf,
                                                        int E) {
    __shared__ unsigned int vals[TILE];
    __shared__ unsigned short bid[TILE];
    __shared__ int hist[BMAX];
    __shared__ int lcur[BMAX];
    __shared__ int goff[BMAX];
    __shared__ int sc[256];
    int t = threadIdx.x;
    int tile_base = blockIdx.x * TILE;
    int n_tile = min(TILE, E - tile_base);

    for (int i = t; i < BMAX; i += 256) hist[i] = 0;
    __syncthreads();

    unsigned int pk[TILE / 256];
    int bk[TILE / 256];
#pragma unroll
    for (int k = 0; k < TILE / 256; ++k) {
        int e = tile_base + k * 256 + t;
        if (e < E) {
            int s = src[e], d = dst[e];
            int b = d >> 7;
            pk[k] = ((unsigned)s << 7) | (unsigned)(d & 127);
            bk[k] = b;
            atomicAdd(&hist[b], 1);
        } else bk[k] = -1;
    }
    __syncthreads();

    int base4 = t * 4;
    int sum4 = hist[base4] + hist[base4 + 1] + hist[base4 + 2] + hist[base4 + 3];
    sc[t] = sum4;
    __syncthreads();
    for (int off = 1; off < 256; off <<= 1) {
        int v = (t >= off) ? sc[t - off] : 0;
        __syncthreads();
        sc[t] += v;
        __syncthreads();
    }
    int run = sc[t] - sum4;
#pragma unroll
    for (int j = 0; j < 4; ++j) {
        int tmp = hist[base4 + j];
        hist[base4 + j] = run;
        lcur[base4 + j] = run;
        run += tmp;
    }
    __syncthreads();

#pragma unroll
    for (int k = 0; k < TILE / 256; ++k) {
        if (bk[k] >= 0) {
            int pos = atomicAdd(&lcur[bk[k]], 1);
            vals[pos] = pk[k];
            bid[pos] = (unsigned short)bk[k];
        }
    }
    __syncthreads();

    for (int b = t; b < BMAX; b += 256) {
        int cnt = lcur[b] - hist[b];
        goff[b] = (cnt > 0) ? atomicAdd(&gcursor[b], cnt) : 0;
    }
    __syncthreads();

    for (int i = t; i < n_tile; i += 256) {
        int b = bid[i];
        int addr = goff[b] + (i - hist[b]);
        if (addr < (b + 1) * CAP)
            bucket_buf[addr] = vals[i];
    }
}

// ---------------- per-bucket CSR build (in place) ----------------
__global__ __launch_bounds__(256) void bucket_csr_kernel(unsigned int* bucket_buf,
                                                         const int* __restrict__ gcursor,
                                                         int* __restrict__ row_start,
                                                         int* __restrict__ degA,
                                                         float* __restrict__ dinv,
                                                         int N) {
    __shared__ int ldeg[128], lexc[128], lcur2[128];
    __shared__ int colLDS[CAP];
    int b = blockIdx.x;
    int t = threadIdx.x;
    int base = b * CAP;
    int cnt = min(gcursor[b] - base, CAP);

    if (t < 128) ldeg[t] = 0;
    __syncthreads();
    for (int i = t; i < cnt; i += 256)
        atomicAdd(&ldeg[bucket_buf[base + i] & 127], 1);
    __syncthreads();

    if (t < 128) lexc[t] = ldeg[t];
    __syncthreads();
    for (int off = 1; off < 128; off <<= 1) {
        int v = (t >= off && t < 128) ? lexc[t - off] : 0;
        __syncthreads();
        if (t < 128) lexc[t] += v;
        __syncthreads();
    }
    if (t < 128) {
        int ex = lexc[t] - ldeg[t];
        lcur2[t] = ex;
        int node = (b << 7) + t;
        if (node < N) {
            row_start[node] = base + ex;
            degA[node] = ldeg[t];
            dinv[node] = rsqrtf(fmaxf((float)ldeg[t], 1.0f));
        }
    }
    __syncthreads();

    for (int i = t; i < cnt; i += 256) {
        unsigned int v = bucket_buf[base + i];
        int pos = atomicAdd(&lcur2[(int)(v & 127)], 1);
        colLDS[pos] = (int)(v >> 7);
    }
    __syncthreads();
    for (int i = t; i < cnt; i += 256)
        bucket_buf[base + i] = (unsigned int)colLDS[i];   // now = col[]
}

// ---------------- MLP in via MFMA: h = relu(feat@W1+b1)@W2+b2 ----------------
// Weights staged once per block in LDS as bf16 fragments; 4 waves x 16-node
// M-tiles; mfma_f32_16x16x32_bf16 for both layers. A/B frags use a COMMON
// k-bijection (k = 8*(lane>>4)+e) so the true per-slot k order cancels;
// C/D layout (col=lane&15, row=4*(lane>>4)+reg) is HW-verified.
__global__ __launch_bounds__(256) void mlp_kernel(const float* __restrict__ feat,
                                                  const float* __restrict__ W1,
                                                  const float* __restrict__ b1,
                                                  const float* __restrict__ W2,
                                                  const float* __restrict__ b2,
                                                  const float* __restrict__ dinv,
                                                  float* __restrict__ hout,
                                                  uint4* __restrict__ hs_b, int N) {
    __shared__ unsigned short w1t[32][72];      // W1^T [j][k], pad 64->72 (row 144B, 16B-aligned)
    __shared__ unsigned short w2t[32][40];      // W2^T [j][k], pad 32->40 (row 80B)
    __shared__ unsigned short h1t[4][16][40];   // per-wave relu(h1) [row][j] bf16
    __shared__ unsigned short h2t[4][16][40];   // per-wave dinv*h2   [row][j] bf16

    int lt = threadIdx.x;
    // cooperative weight staging (fp32 -> bf16, transposed)
    for (int i = lt; i < FIN * HD; i += 256) {
        int k = i >> 5, j = i & 31;
        w1t[j][k] = (unsigned short)f2bf(W1[i]);
    }
    for (int i = lt; i < HD * HD; i += 256) {
        int k = i >> 5, j = i & 31;
        w2t[j][k] = (unsigned short)f2bf(W2[i]);
    }
    __syncthreads();

    int w = lt >> 6;            // wave id 0..3
    int l = lt & 63;            // lane
    int g = l >> 4;             // lane group 0..3
    int c = l & 15;             // tile row (A) / tile col (B,D)
    int base = blockIdx.x * 64 + w * 16;   // first node of this wave's 16-row tile

    // ---- layer-1 A fragments: feat rows (bf16 on the fly), k = ks*32 + 8g + e ----
    int row = base + c;
    int rowc = (row < N) ? row : (N - 1);
    const float* fr = feat + (size_t)rowc * FIN;
    bf16x8 a1[2];
#pragma unroll
    for (int ks = 0; ks < 2; ++ks) {
        const float4* p = (const float4*)(fr + ks * 32 + 8 * g);
        float4 u0 = p[0], u1 = p[1];
        bf16x8 a;
        a[0] = (short)f2bf(u0.x); a[1] = (short)f2bf(u0.y);
        a[2] = (short)f2bf(u0.z); a[3] = (short)f2bf(u0.w);
        a[4] = (short)f2bf(u1.x); a[5] = (short)f2bf(u1.y);
        a[6] = (short)f2bf(u1.z); a[7] = (short)f2bf(u1.w);
        a1[ks] = a;
    }

    // ---- layer 1 MFMA: acc[nt] = sum_ks feat_tile @ W1[:, nt*16..] ----
    f32x4 acc[2];
#pragma unroll
    for (int nt = 0; nt < 2; ++nt) { acc[nt][0] = 0.f; acc[nt][1] = 0.f; acc[nt][2] = 0.f; acc[nt][3] = 0.f; }
#pragma unroll
    for (int nt = 0; nt < 2; ++nt) {
#pragma unroll
        for (int ks = 0; ks < 2; ++ks) {
            bf16x8 b = *(const bf16x8*)&w1t[nt * 16 + c][ks * 32 + 8 * g];
            acc[nt] = __builtin_amdgcn_mfma_f32_16x16x32_bf16(a1[ks], b, acc[nt], 0, 0, 0);
        }
    }

    // ---- bias + relu -> bf16 LDS tile (row-major) ----
    float b1v0 = b1[c], b1v1 = b1[16 + c];
#pragma unroll
    for (int r = 0; r < 4; ++r) {
        h1t[w][4 * g + r][c]      = (unsigned short)f2bf(fmaxf(acc[0][r] + b1v0, 0.0f));
        h1t[w][4 * g + r][16 + c] = (unsigned short)f2bf(fmaxf(acc[1][r] + b1v1, 0.0f));
    }
    __syncthreads();

    // ---- layer 2 MFMA: A frag from h1 tile (row c, k = 8g+e) ----
    bf16x8 a2 = *(const bf16x8*)&h1t[w][c][8 * g];
    f32x4 acc2[2];
#pragma unroll
    for (int nt = 0; nt < 2; ++nt) { acc2[nt][0] = 0.f; acc2[nt][1] = 0.f; acc2[nt][2] = 0.f; acc2[nt][3] = 0.f; }
#pragma unroll
    for (int nt = 0; nt < 2; ++nt) {
        bf16x8 b = *(const bf16x8*)&w2t[nt * 16 + c][8 * g];
        acc2[nt] = __builtin_amdgcn_mfma_f32_16x16x32_bf16(a2, b, acc2[nt], 0, 0, 0);
    }

    // ---- bias, write h (fp32) + stage dinv*h2 bf16 for hs_b packing ----
    float b2v0 = b2[c], b2v1 = b2[16 + c];
#pragma unroll
    for (int r = 0; r < 4; ++r) {
        int rr = base + 4 * g + r;
        int rc = (rr < N) ? rr : (N - 1);
        float dv = dinv[rc];
        float v0 = acc2[0][r] + b2v0;
        float v1 = acc2[1][r] + b2v1;
        if (rr < N) {
            hout[(size_t)rr * HD + c]      = v0;
            hout[(size_t)rr * HD + 16 + c] = v1;
        }
        h2t[w][4 * g + r][c]      = (unsigned short)f2bf(dv * v0);
        h2t[w][4 * g + r][16 + c] = (unsigned short)f2bf(dv * v1);
    }
    __syncthreads();

    // ---- pack hs_b: lane handles tile-row c, feature block g (8 bf16 = 16B) ----
    int nrow = base + c;
    if (nrow < N) {
        uint4 u = *(const uint4*)&h2t[w][c][8 * g];
        hs_b[(size_t)nrow * 4 + g] = u;
    }
}

// ---------------- gather #1: acc = sum hs[col]; s0 = acc (fp32);
//                  f1s_b = bf16(dinv[n]*(h[n] + dinv[n]*acc)) ----------------
// 4 lanes/node, lane q handles features [8q, 8q+8); edge loop unrolled x4 so
// 4 col->data chains are in flight (was 1 -> latency-bound).
__global__ __launch_bounds__(256) void gather1_kernel(const float* __restrict__ h,
                                                      const uint4* __restrict__ hs_b,
                                                      const float* __restrict__ dinv,
                                                      const int* __restrict__ row_start,
                                                      const int* __restrict__ deg,
                                                      const int* __restrict__ col,
                                                      float* __restrict__ s0,
                                                      uint4* __restrict__ f1s_b, int N) {
    int t = blockIdx.x * 256 + threadIdx.x;
    int n = t >> 2;
    if (n >= N) return;
    int q = t & 3;
    int s = row_start[n];
    int e_end = s + deg[n];
    float acc[8] = {0.f, 0.f, 0.f, 0.f, 0.f, 0.f, 0.f, 0.f};
    int e = s;
    for (; e + 4 <= e_end; e += 4) {
        int c0 = col[e], c1 = col[e + 1], c2 = col[e + 2], c3 = col[e + 3];
        uint4 v0 = hs_b[(size_t)c0 * 4 + q];
        uint4 v1 = hs_b[(size_t)c1 * 4 + q];
        uint4 v2 = hs_b[(size_t)c2 * 4 + q];
        uint4 v3 = hs_b[(size_t)c3 * 4 + q];
        acc[0] += (bflo(v0.x) + bflo(v1.x)) + (bflo(v2.x) + bflo(v3.x));
        acc[1] += (bfhi(v0.x) + bfhi(v1.x)) + (bfhi(v2.x) + bfhi(v3.x));
        acc[2] += (bflo(v0.y) + bflo(v1.y)) + (bflo(v2.y) + bflo(v3.y));
        acc[3] += (bfhi(v0.y) + bfhi(v1.y)) + (bfhi(v2.y) + bfhi(v3.y));
        acc[4] += (bflo(v0.z) + bflo(v1.z)) + (bflo(v2.z) + bflo(v3.z));
        acc[5] += (bfhi(v0.z) + bfhi(v1.z)) + (bfhi(v2.z) + bfhi(v3.z));
        acc[6] += (bflo(v0.w) + bflo(v1.w)) + (bflo(v2.w) + bflo(v3.w));
        acc[7] += (bfhi(v0.w) + bfhi(v1.w)) + (bfhi(v2.w) + bfhi(v3.w));
    }
    for (; e < e_end; ++e) {
        int c = col[e];
        uint4 v = hs_b[(size_t)c * 4 + q];
        acc[0] += bflo(v.x); acc[1] += bfhi(v.x);
        acc[2] += bflo(v.y); acc[3] += bfhi(v.y);
        acc[4] += bflo(v.z); acc[5] += bfhi(v.z);
        acc[6] += bflo(v.w); acc[7] += bfhi(v.w);
    }
    float di = dinv[n];
    const float4* h4 = (const float4*)h;
    float4 ha = h4[(size_t)n * 8 + 2 * q];
    float4 hb = h4[(size_t)n * 8 + 2 * q + 1];
    float f[8] = {fmaf(di, acc[0], ha.x), fmaf(di, acc[1], ha.y),
                  fmaf(di, acc[2], ha.z), fmaf(di, acc[3], ha.w),
                  fmaf(di, acc[4], hb.x), fmaf(di, acc[5], hb.y),
                  fmaf(di, acc[6], hb.z), fmaf(di, acc[7], hb.w)};
    float4 sa = {acc[0], acc[1], acc[2], acc[3]};
    float4 sb = {acc[4], acc[5], acc[6], acc[7]};
    ((float4*)s0)[(size_t)n * 8 + 2 * q] = sa;
    ((float4*)s0)[(size_t)n * 8 + 2 * q + 1] = sb;
    uint4 u;
    u.x = pack2(di * f[0], di * f[1]);
    u.y = pack2(di * f[2], di * f[3]);
    u.z = pack2(di * f[4], di * f[5]);
    u.w = pack2(di * f[6], di * f[7]);
    f1s_b[(size_t)n * 4 + q] = u;
}

// ---------------- fused gather #2 + epilogue ----------------
// t1 = sum f1s[col] gathered in-kernel (no t1 round-trip through HBM);
// 8 own features exchanged across the 4-lane group via LDS ([256][9] pad:
// 2-way bank conflicts = free). All threads reach the barrier (clamped tail).
// Bases: f2 = h + d*s0 + d*t1; g1 = h + d*s0 - d*t1; g2 = h - 3d*s0 + d*t1
__global__ __launch_bounds__(256) void final_kernel(const float* __restrict__ h,
                                                    const float* __restrict__ s0,
                                                    const uint4* __restrict__ f1s_b,
                                                    const float* __restrict__ dinv,
                                                    const int* __restrict__ row_start,
                                                    const int* __restrict__ deg,
                                                    const int* __restrict__ col,
                                                    const float* __restrict__ W2,
                                                    const float* __restrict__ b2,
                                                    const float* __restrict__ Wc,
                                                    const float* __restrict__ bc,
                                                    const float* __restrict__ wbern,
                                                    float* __restrict__ out, int N) {
    __shared__ float t1x[256][9];
    int lt = threadIdx.x;
    int t = blockIdx.x * 256 + lt;
    int n = t >> 2;
    int nc = (n < N) ? n : (N - 1);   // clamp; guard stores only
    int q = t & 3;
    int jb = 8 * q;
    int g4 = lt & ~3;

    // ---- gather t1 (own 8 features), unrolled x4 ----
    int s = row_start[nc];
    int e_end = s + deg[nc];
    float acc[8] = {0.f, 0.f, 0.f, 0.f, 0.f, 0.f, 0.f, 0.f};
    int e = s;
    for (; e + 4 <= e_end; e += 4) {
        int c0 = col[e], c1 = col[e + 1], c2 = col[e + 2], c3 = col[e + 3];
        uint4 v0 = f1s_b[(size_t)c0 * 4 + q];
        uint4 v1 = f1s_b[(size_t)c1 * 4 + q];
        uint4 v2 = f1s_b[(size_t)c2 * 4 + q];
        uint4 v3 = f1s_b[(size_t)c3 * 4 + q];
        acc[0] += (bflo(v0.x) + bflo(v1.x)) + (bflo(v2.x) + bflo(v3.x));
        acc[1] += (bfhi(v0.x) + bfhi(v1.x)) + (bfhi(v2.x) + bfhi(v3.x));
        acc[2] += (bflo(v0.y) + bflo(v1.y)) + (bflo(v2.y) + bflo(v3.y));
        acc[3] += (bfhi(v0.y) + bfhi(v1.y)) + (bfhi(v2.y) + bfhi(v3.y));
        acc[4] += (bflo(v0.z) + bflo(v1.z)) + (bflo(v2.z) + bflo(v3.z));
        acc[5] += (bfhi(v0.z) + bfhi(v1.z)) + (bfhi(v2.z) + bfhi(v3.z));
        acc[6] += (bflo(v0.w) + bflo(v1.w)) + (bflo(v2.w) + bflo(v3.w));
        acc[7] += (bfhi(v0.w) + bfhi(v1.w)) + (bfhi(v2.w) + bfhi(v3.w));
    }
    for (; e < e_end; ++e) {
        int c = col[e];
        uint4 v = f1s_b[(size_t)c * 4 + q];
        acc[0] += bflo(v.x); acc[1] += bfhi(v.x);
        acc[2] += bflo(v.y); acc[3] += bfhi(v.y);
        acc[4] += bflo(v.z); acc[5] += bfhi(v.z);
        acc[6] += bflo(v.w); acc[7] += bfhi(v.w);
    }
#pragma unroll
    for (int j = 0; j < 8; ++j) t1x[lt][j] = acc[j];
    __syncthreads();

    float di = dinv[nc];

    float4 b2a = ((const float4*)b2)[2 * q];
    float4 b2b = ((const float4*)b2)[2 * q + 1];
    float b2v[8] = {b2a.x, b2a.y, b2a.z, b2a.w, b2b.x, b2b.y, b2b.z, b2b.w};

    float xp[8];
#pragma unroll
    for (int j = 0; j < 8; ++j) xp[j] = b2v[j];
    float uf[8], ug[8], uh[8];
#pragma unroll
    for (int j = 0; j < 8; ++j) { uf[j] = 0.f; ug[j] = 0.f; uh[j] = 0.f; }
    float vf0 = 0.f, vf1 = 0.f, vg0 = 0.f, vg1 = 0.f, vh0 = 0.f, vh1 = 0.f;

    const float4* h4  = (const float4*)(h  + (size_t)nc * HD);
    const float4* s04 = (const float4*)(s0 + (size_t)nc * HD);
    const float2* wc2 = (const float2*)Wc;

#pragma unroll
    for (int q8 = 0; q8 < 8; ++q8) {
        float4 hv = h4[q8];
        float4 av = s04[q8];
        int trow = g4 + (q8 >> 1);
        int tcol = (q8 & 1) * 4;
        float hq[4] = {hv.x, hv.y, hv.z, hv.w};
        float da[4] = {di * av.x, di * av.y, di * av.z, di * av.w};
        float db[4] = {di * t1x[trow][tcol + 0], di * t1x[trow][tcol + 1],
                       di * t1x[trow][tcol + 2], di * t1x[trow][tcol + 3]};
#pragma unroll
        for (int r = 0; r < 4; ++r) {
            int k = q8 * 4 + r;
            float f2 = hq[r] + da[r] + db[r];
            float g1 = hq[r] + da[r] - db[r];
            float g2 = hq[r] - 3.0f * da[r] + db[r];
            const float4* w4 = (const float4*)&W2[k * HD + jb];
            float4 wA = w4[0], wB = w4[1];
            float wv[8] = {wA.x, wA.y, wA.z, wA.w, wB.x, wB.y, wB.z, wB.w};
#pragma unroll
            for (int j = 0; j < 8; ++j) {
                xp[j] = fmaf(hq[r], wv[j], xp[j]);
                uf[j] = fmaf(f2, wv[j], uf[j]);
                ug[j] = fmaf(g1, wv[j], ug[j]);
                uh[j] = fmaf(g2, wv[j], uh[j]);
            }
            float2 wc = wc2[k];
            vf0 = fmaf(f2, wc.x, vf0); vf1 = fmaf(f2, wc.y, vf1);
            vg0 = fmaf(g1, wc.x, vg0); vg1 = fmaf(g1, wc.y, vg1);
            vh0 = fmaf(g2, wc.x, vh0); vh1 = fmaf(g2, wc.y, vh1);
        }
    }

#pragma unroll
    for (int j = 0; j < 8; ++j) xp[j] = fast_tanh(xp[j]);

    float logits[NL];
#pragma unroll
    for (int i = 0; i < NL; ++i) {
        float wa = 0.25f * fmaxf(wbern[i * 3 + 0], 0.0f);
        float wb = 0.50f * fmaxf(wbern[i * 3 + 1], 0.0f);
        float wc = 0.25f * fmaxf(wbern[i * 3 + 2], 0.0f);
        float lg = 0.0f;
#pragma unroll
        for (int j = 0; j < 8; ++j) {
            float p = fmaf(wa, uf[j], fmaf(wb, ug[j], fmaf(wc, uh[j], b2v[j])));
            lg = fmaf(fast_tanh(p), xp[j], lg);
        }
        lg += __shfl_xor(lg, 1);
        lg += __shfl_xor(lg, 2);
        logits[i] = lg;
    }

    float m = fmaxf(logits[0], fmaxf(logits[1], logits[2]));
    float e0 = __expf(logits[0] - m), e1 = __expf(logits[1] - m), e2 = __expf(logits[2] - m);
    float inv = 1.0f / (e0 + e1 + e2);
    float scs[NL] = {e0 * inv, e1 * inv, e2 * inv};

    float A = 0.0f, B = 0.0f, Cc = 0.0f;
#pragma unroll
    for (int i = 0; i < NL; ++i) {
        A  += scs[i] * 0.25f * fmaxf(wbern[i * 3 + 0], 0.0f);
        B  += scs[i] * 0.50f * fmaxf(wbern[i * 3 + 1], 0.0f);
        Cc += scs[i] * 0.25f * fmaxf(wbern[i * 3 + 2], 0.0f);
    }
    if (q == 0 && n < N) {
        float2 o;
        o.x = bc[0] + A * vf0 + B * vg0 + Cc * vh0;
        o.y = bc[1] + A * vf1 + B * vg1 + Cc * vh1;
        ((float2*)out)[n] = o;
    }
}

extern "C" void kernel_launch(void* const* d_in, const int* in_sizes, int n_in,
                              void* d_out, int out_size, void* d_ws, size_t ws_size,
                              hipStream_t stream) {
    const float* feature = (const float*)d_in[0];
    const float* W1 = (const float*)d_in[1];
    const float* b1 = (const float*)d_in[2];
    const float* W2 = (const float*)d_in[3];
    const float* b2 = (const float*)d_in[4];
    const float* Wc = (const float*)d_in[5];
    const float* bc = (const float*)d_in[6];
    const float* wbern = (const float*)d_in[7];
    const int* src = (const int*)d_in[8];
    const int* dst = (const int*)d_in[9];

    const int N = in_sizes[0] / FIN;   // 100000
    const int E = in_sizes[8];         // 1600000
    const int B = (N + 127) >> 7;      // 782 buckets

    // workspace layout
    char* p = (char*)d_ws;
    size_t Np = ((size_t)N + 255) & ~(size_t)255;
    size_t N32 = (size_t)N * HD;
    int* gcursor   = (int*)p;              p += ((size_t)BMAX) * 4;
    int* row_start = (int*)p;              p += Np * 4;
    int* degA      = (int*)p;              p += Np * 4;
    float* dinv    = (float*)p;            p += Np * 4;
    unsigned int* bucket_buf = (unsigned int*)p;  p += (size_t)B * CAP * 4;  // becomes col[]
    float* h    = (float*)p;               p += N32 * 4;
    float* s0   = (float*)p;               p += N32 * 4;
    uint4* hs_b = (uint4*)p;               p += N32 * 2;   // bf16, 64B/row
    uint4* f1s_b= (uint4*)p;               p += N32 * 2;

    int bG = ((N * 4) + 255) / 256;        // 4 lanes per node
    int bM = (N + 63) / 64;                // 64 nodes per block (4 waves x 16)
    int nTiles = (E + TILE - 1) / TILE;

    init_kernel<<<(B + 255) / 256, 256, 0, stream>>>(gcursor, B);
    partition_kernel<<<nTiles, 256, 0, stream>>>(src, dst, gcursor, bucket_buf, E);
    bucket_csr_kernel<<<B, 256, 0, stream>>>(bucket_buf, gcursor, row_start, degA, dinv, N);

    mlp_kernel<<<bM, 256, 0, stream>>>(feature, W1, b1, W2, b2, dinv, h, hs_b, N);

    const int* col = (const int*)bucket_buf;
    gather1_kernel<<<bG, 256, 0, stream>>>(h, hs_b, dinv, row_start, degA, col, s0, f1s_b, N);

    final_kernel<<<bG, 256, 0, stream>>>(h, s0, f1s_b, dinv, row_start, degA, col,
                                         W2, b2, Wc, bc, wbern, (float*)d_out, N);
}

// Round 5
// 186.906 us; speedup vs baseline: 1.3765x; 1.1595x over previous
//
#include <hip/hip_runtime.h>
#include <math.h>

#define HD 32      // hidden dim
#define FIN 64     // input features
#define NL 3       // num BernConv layers
#define NC 2       // num classes

#define TILE 4096  // edges per partition tile
#define CAP  3072  // max edges per bucket (mean ~2046, 12 sigma margin)
#define BMAX 1024  // max buckets (N <= 131072 with 128 nodes/bucket)

typedef __attribute__((ext_vector_type(8))) short bf16x8;
typedef __attribute__((ext_vector_type(4))) float f32x4;

// fast tanh; |rel err| ~1e-7, threshold 7e-2
__device__ __forceinline__ float fast_tanh(float x) {
    float e = __expf(2.0f * x);
    return 1.0f - 2.0f * __builtin_amdgcn_rcpf(e + 1.0f);
}

// fp32 -> bf16 bits with round-to-nearest-even (values are finite here)
__device__ __forceinline__ unsigned int f2bf(float f) {
    unsigned int u = __float_as_uint(f);
    return (u + 0x7fffu + ((u >> 16) & 1u)) >> 16;
}
__device__ __forceinline__ unsigned int pack2(float lo, float hi) {
    return f2bf(lo) | (f2bf(hi) << 16);
}
// bf16 pair -> fp32 (exact, just bit shifts)
__device__ __forceinline__ float bflo(unsigned int u) { return __uint_as_float(u << 16); }
__device__ __forceinline__ float bfhi(unsigned int u) { return __uint_as_float(u & 0xffff0000u); }

// split x into bf16 hi + bf16 lo (residual); hi+lo recovers x to ~2^-17 rel
__device__ __forceinline__ void pack_hilo(const float* v, bf16x8& hi, bf16x8& lo) {
#pragma unroll
    for (int e = 0; e < 8; ++e) {
        unsigned int uh = f2bf(v[e]);
        float xh = __uint_as_float(uh << 16);
        unsigned int ul = f2bf(v[e] - xh);
        hi[e] = (short)uh;
        lo[e] = (short)ul;
    }
}

// ---------------- gcursor init ----------------
__global__ __launch_bounds__(256) void init_kernel(int* __restrict__ gcursor, int B) {
    int b = blockIdx.x * 256 + threadIdx.x;
    if (b < B) gcursor[b] = b * CAP;
}

// ---------------- LDS-staged partition: bucket edges by dst>>7 ----------------
__global__ __launch_bounds__(256) void partition_kernel(const int* __restrict__ src,
                                                        const int* __restrict__ dst,
                                                        int* __restrict__ gcursor,
                                                        unsigned int* __restrict__ bucket_buf,
                                                        int E) {
    __shared__ unsigned int vals[TILE];
    __shared__ unsigned short bid[TILE];
    __shared__ int hist[BMAX];
    __shared__ int lcur[BMAX];
    __shared__ int goff[BMAX];
    __shared__ int sc[256];
    int t = threadIdx.x;
    int tile_base = blockIdx.x * TILE;
    int n_tile = min(TILE, E - tile_base);

    for (int i = t; i < BMAX; i += 256) hist[i] = 0;
    __syncthreads();

    unsigned int pk[TILE / 256];
    int bk[TILE / 256];
#pragma unroll
    for (int k = 0; k < TILE / 256; ++k) {
        int e = tile_base + k * 256 + t;
        if (e < E) {
            int s = src[e], d = dst[e];
            int b = d >> 7;
            pk[k] = ((unsigned)s << 7) | (unsigned)(d & 127);
            bk[k] = b;
            atomicAdd(&hist[b], 1);
        } else bk[k] = -1;
    }
    __syncthreads();

    int base4 = t * 4;
    int sum4 = hist[base4] + hist[base4 + 1] + hist[base4 + 2] + hist[base4 + 3];
    sc[t] = sum4;
    __syncthreads();
    for (int off = 1; off < 256; off <<= 1) {
        int v = (t >= off) ? sc[t - off] : 0;
        __syncthreads();
        sc[t] += v;
        __syncthreads();
    }
    int run = sc[t] - sum4;
#pragma unroll
    for (int j = 0; j < 4; ++j) {
        int tmp = hist[base4 + j];
        hist[base4 + j] = run;
        lcur[base4 + j] = run;
        run += tmp;
    }
    __syncthreads();

#pragma unroll
    for (int k = 0; k < TILE / 256; ++k) {
        if (bk[k] >= 0) {
            int pos = atomicAdd(&lcur[bk[k]], 1);
            vals[pos] = pk[k];
            bid[pos] = (unsigned short)bk[k];
        }
    }
    __syncthreads();

    for (int b = t; b < BMAX; b += 256) {
        int cnt = lcur[b] - hist[b];
        goff[b] = (cnt > 0) ? atomicAdd(&gcursor[b], cnt) : 0;
    }
    __syncthreads();

    for (int i = t; i < n_tile; i += 256) {
        int b = bid[i];
        int addr = goff[b] + (i - hist[b]);
        if (addr < (b + 1) * CAP)
            bucket_buf[addr] = vals[i];
    }
}

// ---------------- per-bucket CSR build (in place) ----------------
__global__ __launch_bounds__(256) void bucket_csr_kernel(unsigned int* bucket_buf,
                                                         const int* __restrict__ gcursor,
                                                         int* __restrict__ row_start,
                                                         int* __restrict__ degA,
                                                         float* __restrict__ dinv,
                                                         int N) {
    __shared__ int ldeg[128], lexc[128], lcur2[128];
    __shared__ int colLDS[CAP];
    int b = blockIdx.x;
    int t = threadIdx.x;
    int base = b * CAP;
    int cnt = min(gcursor[b] - base, CAP);

    if (t < 128) ldeg[t] = 0;
    __syncthreads();
    for (int i = t; i < cnt; i += 256)
        atomicAdd(&ldeg[bucket_buf[base + i] & 127], 1);
    __syncthreads();

    if (t < 128) lexc[t] = ldeg[t];
    __syncthreads();
    for (int off = 1; off < 128; off <<= 1) {
        int v = (t >= off && t < 128) ? lexc[t - off] : 0;
        __syncthreads();
        if (t < 128) lexc[t] += v;
        __syncthreads();
    }
    if (t < 128) {
        int ex = lexc[t] - ldeg[t];
        lcur2[t] = ex;
        int node = (b << 7) + t;
        if (node < N) {
            row_start[node] = base + ex;
            degA[node] = ldeg[t];
            dinv[node] = rsqrtf(fmaxf((float)ldeg[t], 1.0f));
        }
    }
    __syncthreads();

    for (int i = t; i < cnt; i += 256) {
        unsigned int v = bucket_buf[base + i];
        int pos = atomicAdd(&lcur2[(int)(v & 127)], 1);
        colLDS[pos] = (int)(v >> 7);
    }
    __syncthreads();
    for (int i = t; i < cnt; i += 256)
        bucket_buf[base + i] = (unsigned int)colLDS[i];   // now = col[]
}

// ---------------- MLP in via MFMA: h = relu(feat@W1+b1)@W2+b2 ----------------
// Weights staged once per block in LDS as bf16 fragments; 4 waves x 16-node
// M-tiles; mfma_f32_16x16x32_bf16 for both layers. A/B frags use a COMMON
// k-bijection (k = 8*(lane>>4)+e) so the true per-slot k order cancels;
// C/D layout (col=lane&15, row=4*(lane>>4)+reg) is HW-verified.
__global__ __launch_bounds__(256) void mlp_kernel(const float* __restrict__ feat,
                                                  const float* __restrict__ W1,
                                                  const float* __restrict__ b1,
                                                  const float* __restrict__ W2,
                                                  const float* __restrict__ b2,
                                                  const float* __restrict__ dinv,
                                                  float* __restrict__ hout,
                                                  uint4* __restrict__ hs_b, int N) {
    __shared__ unsigned short w1t[32][72];      // W1^T [j][k], pad 64->72 (row 144B, 16B-aligned)
    __shared__ unsigned short w2t[32][40];      // W2^T [j][k], pad 32->40 (row 80B)
    __shared__ unsigned short h1t[4][16][40];   // per-wave relu(h1) [row][j] bf16
    __shared__ unsigned short h2t[4][16][40];   // per-wave dinv*h2   [row][j] bf16

    int lt = threadIdx.x;
    // cooperative weight staging (fp32 -> bf16, transposed)
    for (int i = lt; i < FIN * HD; i += 256) {
        int k = i >> 5, j = i & 31;
        w1t[j][k] = (unsigned short)f2bf(W1[i]);
    }
    for (int i = lt; i < HD * HD; i += 256) {
        int k = i >> 5, j = i & 31;
        w2t[j][k] = (unsigned short)f2bf(W2[i]);
    }
    __syncthreads();

    int w = lt >> 6;            // wave id 0..3
    int l = lt & 63;            // lane
    int g = l >> 4;             // lane group 0..3
    int c = l & 15;             // tile row (A) / tile col (B,D)
    int base = blockIdx.x * 64 + w * 16;   // first node of this wave's 16-row tile

    // ---- layer-1 A fragments: feat rows (bf16 on the fly), k = ks*32 + 8g + e ----
    int row = base + c;
    int rowc = (row < N) ? row : (N - 1);
    const float* fr = feat + (size_t)rowc * FIN;
    bf16x8 a1[2];
#pragma unroll
    for (int ks = 0; ks < 2; ++ks) {
        const float4* p = (const float4*)(fr + ks * 32 + 8 * g);
        float4 u0 = p[0], u1 = p[1];
        bf16x8 a;
        a[0] = (short)f2bf(u0.x); a[1] = (short)f2bf(u0.y);
        a[2] = (short)f2bf(u0.z); a[3] = (short)f2bf(u0.w);
        a[4] = (short)f2bf(u1.x); a[5] = (short)f2bf(u1.y);
        a[6] = (short)f2bf(u1.z); a[7] = (short)f2bf(u1.w);
        a1[ks] = a;
    }

    // ---- layer 1 MFMA: acc[nt] = sum_ks feat_tile @ W1[:, nt*16..] ----
    f32x4 acc[2];
#pragma unroll
    for (int nt = 0; nt < 2; ++nt) { acc[nt][0] = 0.f; acc[nt][1] = 0.f; acc[nt][2] = 0.f; acc[nt][3] = 0.f; }
#pragma unroll
    for (int nt = 0; nt < 2; ++nt) {
#pragma unroll
        for (int ks = 0; ks < 2; ++ks) {
            bf16x8 b = *(const bf16x8*)&w1t[nt * 16 + c][ks * 32 + 8 * g];
            acc[nt] = __builtin_amdgcn_mfma_f32_16x16x32_bf16(a1[ks], b, acc[nt], 0, 0, 0);
        }
    }

    // ---- bias + relu -> bf16 LDS tile (row-major) ----
    float b1v0 = b1[c], b1v1 = b1[16 + c];
#pragma unroll
    for (int r = 0; r < 4; ++r) {
        h1t[w][4 * g + r][c]      = (unsigned short)f2bf(fmaxf(acc[0][r] + b1v0, 0.0f));
        h1t[w][4 * g + r][16 + c] = (unsigned short)f2bf(fmaxf(acc[1][r] + b1v1, 0.0f));
    }
    __syncthreads();

    // ---- layer 2 MFMA: A frag from h1 tile (row c, k = 8g+e) ----
    bf16x8 a2 = *(const bf16x8*)&h1t[w][c][8 * g];
    f32x4 acc2[2];
#pragma unroll
    for (int nt = 0; nt < 2; ++nt) { acc2[nt][0] = 0.f; acc2[nt][1] = 0.f; acc2[nt][2] = 0.f; acc2[nt][3] = 0.f; }
#pragma unroll
    for (int nt = 0; nt < 2; ++nt) {
        bf16x8 b = *(const bf16x8*)&w2t[nt * 16 + c][8 * g];
        acc2[nt] = __builtin_amdgcn_mfma_f32_16x16x32_bf16(a2, b, acc2[nt], 0, 0, 0);
    }

    // ---- bias, write h (fp32) + stage dinv*h2 bf16 for hs_b packing ----
    float b2v0 = b2[c], b2v1 = b2[16 + c];
#pragma unroll
    for (int r = 0; r < 4; ++r) {
        int rr = base + 4 * g + r;
        int rc = (rr < N) ? rr : (N - 1);
        float dv = dinv[rc];
        float v0 = acc2[0][r] + b2v0;
        float v1 = acc2[1][r] + b2v1;
        if (rr < N) {
            hout[(size_t)rr * HD + c]      = v0;
            hout[(size_t)rr * HD + 16 + c] = v1;
        }
        h2t[w][4 * g + r][c]      = (unsigned short)f2bf(dv * v0);
        h2t[w][4 * g + r][16 + c] = (unsigned short)f2bf(dv * v1);
    }
    __syncthreads();

    // ---- pack hs_b: lane handles tile-row c, feature block g (8 bf16 = 16B) ----
    int nrow = base + c;
    if (nrow < N) {
        uint4 u = *(const uint4*)&h2t[w][c][8 * g];
        hs_b[(size_t)nrow * 4 + g] = u;
    }
}

// ---------------- gather #1: acc = sum hs[col]; s0 = acc (fp32);
//                  f1s_b = bf16(dinv[n]*(h[n] + dinv[n]*acc)) ----------------
// 4 lanes/node, lane q handles features [8q, 8q+8); edge loop unrolled x4 so
// 4 col->data chains are in flight (was 1 -> latency-bound).
__global__ __launch_bounds__(256) void gather1_kernel(const float* __restrict__ h,
                                                      const uint4* __restrict__ hs_b,
                                                      const float* __restrict__ dinv,
                                                      const int* __restrict__ row_start,
                                                      const int* __restrict__ deg,
                                                      const int* __restrict__ col,
                                                      float* __restrict__ s0,
                                                      uint4* __restrict__ f1s_b, int N) {
    int t = blockIdx.x * 256 + threadIdx.x;
    int n = t >> 2;
    if (n >= N) return;
    int q = t & 3;
    int s = row_start[n];
    int e_end = s + deg[n];
    float acc[8] = {0.f, 0.f, 0.f, 0.f, 0.f, 0.f, 0.f, 0.f};
    int e = s;
    for (; e + 4 <= e_end; e += 4) {
        int c0 = col[e], c1 = col[e + 1], c2 = col[e + 2], c3 = col[e + 3];
        uint4 v0 = hs_b[(size_t)c0 * 4 + q];
        uint4 v1 = hs_b[(size_t)c1 * 4 + q];
        uint4 v2 = hs_b[(size_t)c2 * 4 + q];
        uint4 v3 = hs_b[(size_t)c3 * 4 + q];
        acc[0] += (bflo(v0.x) + bflo(v1.x)) + (bflo(v2.x) + bflo(v3.x));
        acc[1] += (bfhi(v0.x) + bfhi(v1.x)) + (bfhi(v2.x) + bfhi(v3.x));
        acc[2] += (bflo(v0.y) + bflo(v1.y)) + (bflo(v2.y) + bflo(v3.y));
        acc[3] += (bfhi(v0.y) + bfhi(v1.y)) + (bfhi(v2.y) + bfhi(v3.y));
        acc[4] += (bflo(v0.z) + bflo(v1.z)) + (bflo(v2.z) + bflo(v3.z));
        acc[5] += (bfhi(v0.z) + bfhi(v1.z)) + (bfhi(v2.z) + bfhi(v3.z));
        acc[6] += (bflo(v0.w) + bflo(v1.w)) + (bflo(v2.w) + bflo(v3.w));
        acc[7] += (bfhi(v0.w) + bfhi(v1.w)) + (bfhi(v2.w) + bfhi(v3.w));
    }
    for (; e < e_end; ++e) {
        int c = col[e];
        uint4 v = hs_b[(size_t)c * 4 + q];
        acc[0] += bflo(v.x); acc[1] += bfhi(v.x);
        acc[2] += bflo(v.y); acc[3] += bfhi(v.y);
        acc[4] += bflo(v.z); acc[5] += bfhi(v.z);
        acc[6] += bflo(v.w); acc[7] += bfhi(v.w);
    }
    float di = dinv[n];
    const float4* h4 = (const float4*)h;
    float4 ha = h4[(size_t)n * 8 + 2 * q];
    float4 hb = h4[(size_t)n * 8 + 2 * q + 1];
    float f[8] = {fmaf(di, acc[0], ha.x), fmaf(di, acc[1], ha.y),
                  fmaf(di, acc[2], ha.z), fmaf(di, acc[3], ha.w),
                  fmaf(di, acc[4], hb.x), fmaf(di, acc[5], hb.y),
                  fmaf(di, acc[6], hb.z), fmaf(di, acc[7], hb.w)};
    float4 sa = {acc[0], acc[1], acc[2], acc[3]};
    float4 sb = {acc[4], acc[5], acc[6], acc[7]};
    ((float4*)s0)[(size_t)n * 8 + 2 * q] = sa;
    ((float4*)s0)[(size_t)n * 8 + 2 * q + 1] = sb;
    uint4 u;
    u.x = pack2(di * f[0], di * f[1]);
    u.y = pack2(di * f[2], di * f[3]);
    u.z = pack2(di * f[4], di * f[5]);
    u.w = pack2(di * f[6], di * f[7]);
    f1s_b[(size_t)n * 4 + q] = u;
}

// ---------------- fused gather #2 + MFMA epilogue ----------------
// Identity: p_i = y_i@W2 + b2 with y_i = al_i*h + be_i*a + ga_i*b (a=d*s0, b=d*t1);
// res = (sum_i score_i*y_i)@Wc. Per 16-node wave tile: 4 matrices {h,y1,y2,y3}
// through W2 via MFMA with A = W2^T (LDS, staged once) and B = data fragments.
// D layout [j=4g+r][node=c]: logit reduce over j is shfl_xor(16/32); scores land
// on the lanes holding node c's y fragments. hi/lo bf16 split on BOTH operands
// (3 MFMAs/product) keeps this path fp32-equivalent; z->Wc stays pure fp32.
// Lane (g,c): node = base+c, k-range [8g,8g+8). No inter-wave barrier after
// weight staging (kills the round-4 block-straggler coupling).
__global__ __launch_bounds__(256) void final_kernel(const float* __restrict__ h,
                                                    const float* __restrict__ s0,
                                                    const uint4* __restrict__ f1s_b,
                                                    const float* __restrict__ dinv,
                                                    const int* __restrict__ row_start,
                                                    const int* __restrict__ deg,
                                                    const int* __restrict__ col,
                                                    const float* __restrict__ W2,
                                                    const float* __restrict__ b2,
                                                    const float* __restrict__ Wc,
                                                    const float* __restrict__ bc,
                                                    const float* __restrict__ wbern,
                                                    float* __restrict__ out, int N) {
    __shared__ unsigned short w2h[32][40];   // bf16 hi of W2^T [j][k], pad 32->40
    __shared__ unsigned short w2l[32][40];   // bf16 lo (residual)

    int lt = threadIdx.x;
    for (int i = lt; i < HD * HD; i += 256) {
        int k = i >> 5, j = i & 31;
        float x = W2[i];
        unsigned int uh = f2bf(x);
        float xh = __uint_as_float(uh << 16);
        w2h[j][k] = (unsigned short)uh;
        w2l[j][k] = (unsigned short)f2bf(x - xh);
    }
    __syncthreads();

    int w = lt >> 6;
    int l = lt & 63;
    int g = l >> 4;             // k-block owner
    int c = l & 15;             // node within wave tile / A-row j
    int node = blockIdx.x * 64 + w * 16 + c;
    int nc = (node < N) ? node : (N - 1);
    int kb = 8 * g;

    // ---- gather t1 for (node, k-block): 4 chains in flight ----
    int s = row_start[nc];
    int e_end = s + deg[nc];
    float acc[8] = {0.f, 0.f, 0.f, 0.f, 0.f, 0.f, 0.f, 0.f};
    int e = s;
    for (; e + 4 <= e_end; e += 4) {
        int c0 = col[e], c1 = col[e + 1], c2 = col[e + 2], c3 = col[e + 3];
        uint4 v0 = f1s_b[(size_t)c0 * 4 + g];
        uint4 v1 = f1s_b[(size_t)c1 * 4 + g];
        uint4 v2 = f1s_b[(size_t)c2 * 4 + g];
        uint4 v3 = f1s_b[(size_t)c3 * 4 + g];
        acc[0] += (bflo(v0.x) + bflo(v1.x)) + (bflo(v2.x) + bflo(v3.x));
        acc[1] += (bfhi(v0.x) + bfhi(v1.x)) + (bfhi(v2.x) + bfhi(v3.x));
        acc[2] += (bflo(v0.y) + bflo(v1.y)) + (bflo(v2.y) + bflo(v3.y));
        acc[3] += (bfhi(v0.y) + bfhi(v1.y)) + (bfhi(v2.y) + bfhi(v3.y));
        acc[4] += (bflo(v0.z) + bflo(v1.z)) + (bflo(v2.z) + bflo(v3.z));
        acc[5] += (bfhi(v0.z) + bfhi(v1.z)) + (bfhi(v2.z) + bfhi(v3.z));
        acc[6] += (bflo(v0.w) + bflo(v1.w)) + (bflo(v2.w) + bflo(v3.w));
        acc[7] += (bfhi(v0.w) + bfhi(v1.w)) + (bfhi(v2.w) + bfhi(v3.w));
    }
    for (; e < e_end; ++e) {
        int cc = col[e];
        uint4 v = f1s_b[(size_t)cc * 4 + g];
        acc[0] += bflo(v.x); acc[1] += bfhi(v.x);
        acc[2] += bflo(v.y); acc[3] += bfhi(v.y);
        acc[4] += bflo(v.z); acc[5] += bfhi(v.z);
        acc[6] += bflo(v.w); acc[7] += bfhi(v.w);
    }

    float di = dinv[nc];
    const float4* hp = (const float4*)(h + (size_t)nc * HD + kb);
    const float4* sp = (const float4*)(s0 + (size_t)nc * HD + kb);
    float4 h0 = hp[0], h1v = hp[1];
    float4 sA = sp[0], sB = sp[1];
    float hv[8] = {h0.x, h0.y, h0.z, h0.w, h1v.x, h1v.y, h1v.z, h1v.w};
    float av[8] = {di * sA.x, di * sA.y, di * sA.z, di * sA.w,
                   di * sB.x, di * sB.y, di * sB.z, di * sB.w};
    float bv[8];
#pragma unroll
    for (int k = 0; k < 8; ++k) bv[k] = di * acc[k];

    // ---- Bern coefficients (uniform over nodes) ----
    float al[NL], be[NL], ga[NL];
#pragma unroll
    for (int i = 0; i < NL; ++i) {
        float wa = 0.25f * fmaxf(wbern[i * 3 + 0], 0.0f);
        float wb = 0.50f * fmaxf(wbern[i * 3 + 1], 0.0f);
        float wc = 0.25f * fmaxf(wbern[i * 3 + 2], 0.0f);
        al[i] = wa + wb + wc;          // coeff of h
        be[i] = wa + wb - 3.0f * wc;   // coeff of a
        ga[i] = wa - wb + wc;          // coeff of b
    }

    // ---- y_i fp32 (kept for the exact z->Wc path) ----
    float y0[8], y1[8], y2[8];
#pragma unroll
    for (int k = 0; k < 8; ++k) {
        y0[k] = fmaf(ga[0], bv[k], fmaf(be[0], av[k], al[0] * hv[k]));
        y1[k] = fmaf(ga[1], bv[k], fmaf(be[1], av[k], al[1] * hv[k]));
        y2[k] = fmaf(ga[2], bv[k], fmaf(be[2], av[k], al[2] * hv[k]));
    }

    // ---- B fragments (data): hi/lo pairs for h, y0, y1, y2 ----
    bf16x8 fbh[4], fbl[4];
    pack_hilo(hv, fbh[0], fbl[0]);
    pack_hilo(y0, fbh[1], fbl[1]);
    pack_hilo(y1, fbh[2], fbl[2]);
    pack_hilo(y2, fbh[3], fbl[3]);

    // ---- MFMA: D[m][jt] = W2^T(jt-tile) @ data_m ; 3 products per pair ----
    f32x4 D[4][2];
#pragma unroll
    for (int m = 0; m < 4; ++m)
#pragma unroll
        for (int jt = 0; jt < 2; ++jt) { D[m][jt][0] = 0.f; D[m][jt][1] = 0.f; D[m][jt][2] = 0.f; D[m][jt][3] = 0.f; }
#pragma unroll
    for (int jt = 0; jt < 2; ++jt) {
        bf16x8 ah = *(const bf16x8*)&w2h[jt * 16 + c][kb];
        bf16x8 alo = *(const bf16x8*)&w2l[jt * 16 + c][kb];
#pragma unroll
        for (int m = 0; m < 4; ++m) {
            D[m][jt] = __builtin_amdgcn_mfma_f32_16x16x32_bf16(ah,  fbh[m], D[m][jt], 0, 0, 0);
            D[m][jt] = __builtin_amdgcn_mfma_f32_16x16x32_bf16(alo, fbh[m], D[m][jt], 0, 0, 0);
            D[m][jt] = __builtin_amdgcn_mfma_f32_16x16x32_bf16(ah,  fbl[m], D[m][jt], 0, 0, 0);
        }
    }

    // ---- bias + tanh; logit partials: lane holds j = jt*16 + 4g + r, node c ----
    float4 b2lo = ((const float4*)b2)[g];       // b2[4g .. 4g+4)
    float4 b2hi = ((const float4*)b2)[4 + g];   // b2[16+4g .. 16+4g+4)
    float b2j[2][4] = {{b2lo.x, b2lo.y, b2lo.z, b2lo.w}, {b2hi.x, b2hi.y, b2hi.z, b2hi.w}};
    float lg[NL] = {0.f, 0.f, 0.f};
#pragma unroll
    for (int jt = 0; jt < 2; ++jt) {
#pragma unroll
        for (int r = 0; r < 4; ++r) {
            float xp = fast_tanh(D[0][jt][r] + b2j[jt][r]);
            lg[0] = fmaf(fast_tanh(D[1][jt][r] + b2j[jt][r]), xp, lg[0]);
            lg[1] = fmaf(fast_tanh(D[2][jt][r] + b2j[jt][r]), xp, lg[1]);
            lg[2] = fmaf(fast_tanh(D[3][jt][r] + b2j[jt][r]), xp, lg[2]);
        }
    }
#pragma unroll
    for (int i = 0; i < NL; ++i) {
        lg[i] += __shfl_xor(lg[i], 16);
        lg[i] += __shfl_xor(lg[i], 32);
    }

    // ---- softmax over 3 filters (redundant across g: fine) ----
    float m = fmaxf(lg[0], fmaxf(lg[1], lg[2]));
    float e0 = __expf(lg[0] - m), e1 = __expf(lg[1] - m), e2 = __expf(lg[2] - m);
    float inv = 1.0f / (e0 + e1 + e2);
    float s0c = e0 * inv, s1c = e1 * inv, s2c = e2 * inv;

    // ---- z = sum_i score_i * y_i (fp32), out = bc + z@Wc (reduce over g) ----
    float o0 = 0.f, o1 = 0.f;
    const float2* wcp = (const float2*)Wc;
#pragma unroll
    for (int k = 0; k < 8; ++k) {
        float z = fmaf(s2c, y2[k], fmaf(s1c, y1[k], s0c * y0[k]));
        float2 wck = wcp[kb + k];
        o0 = fmaf(z, wck.x, o0);
        o1 = fmaf(z, wck.y, o1);
    }
    o0 += __shfl_xor(o0, 16); o0 += __shfl_xor(o0, 32);
    o1 += __shfl_xor(o1, 16); o1 += __shfl_xor(o1, 32);

    if (g == 0 && node < N) {
        float2 o = {bc[0] + o0, bc[1] + o1};
        ((float2*)out)[node] = o;
    }
}

extern "C" void kernel_launch(void* const* d_in, const int* in_sizes, int n_in,
                              void* d_out, int out_size, void* d_ws, size_t ws_size,
                              hipStream_t stream) {
    const float* feature = (const float*)d_in[0];
    const float* W1 = (const float*)d_in[1];
    const float* b1 = (const float*)d_in[2];
    const float* W2 = (const float*)d_in[3];
    const float* b2 = (const float*)d_in[4];
    const float* Wc = (const float*)d_in[5];
    const float* bc = (const float*)d_in[6];
    const float* wbern = (const float*)d_in[7];
    const int* src = (const int*)d_in[8];
    const int* dst = (const int*)d_in[9];

    const int N = in_sizes[0] / FIN;   // 100000
    const int E = in_sizes[8];         // 1600000
    const int B = (N + 127) >> 7;      // 782 buckets

    // workspace layout
    char* p = (char*)d_ws;
    size_t Np = ((size_t)N + 255) & ~(size_t)255;
    size_t N32 = (size_t)N * HD;
    int* gcursor   = (int*)p;              p += ((size_t)BMAX) * 4;
    int* row_start = (int*)p;              p += Np * 4;
    int* degA      = (int*)p;              p += Np * 4;
    float* dinv    = (float*)p;            p += Np * 4;
    unsigned int* bucket_buf = (unsigned int*)p;  p += (size_t)B * CAP * 4;  // becomes col[]
    float* h    = (float*)p;               p += N32 * 4;
    float* s0   = (float*)p;               p += N32 * 4;
    uint4* hs_b = (uint4*)p;               p += N32 * 2;   // bf16, 64B/row
    uint4* f1s_b= (uint4*)p;               p += N32 * 2;

    int bG = ((N * 4) + 255) / 256;        // 4 lanes per node
    int bM = (N + 63) / 64;                // 64 nodes per block (4 waves x 16)
    int nTiles = (E + TILE - 1) / TILE;

    init_kernel<<<(B + 255) / 256, 256, 0, stream>>>(gcursor, B);
    partition_kernel<<<nTiles, 256, 0, stream>>>(src, dst, gcursor, bucket_buf, E);
    bucket_csr_kernel<<<B, 256, 0, stream>>>(bucket_buf, gcursor, row_start, degA, dinv, N);

    mlp_kernel<<<bM, 256, 0, stream>>>(feature, W1, b1, W2, b2, dinv, h, hs_b, N);

    const int* col = (const int*)bucket_buf;
    gather1_kernel<<<bG, 256, 0, stream>>>(h, hs_b, dinv, row_start, degA, col, s0, f1s_b, N);

    final_kernel<<<bM, 256, 0, stream>>>(h, s0, f1s_b, dinv, row_start, degA, col,
                                         W2, b2, Wc, bc, wbern, (float*)d_out, N);
}